// Round 1
// 146.120 us; speedup vs baseline: 1.0315x; 1.0315x over previous
//
#include <hip/hip_runtime.h>
#include <math.h>

// ---------------------------------------------------------------------------
// Barrier_Net, full-f16 MFMA (16x16x32), WAVE-SPLIT pipeline.
// Group = 16 batch rows handled by a PAIR of waves:
//   wave0: stage NBA -> S1N -> G2N -> RNA -> RNB -> CAT cols 0..15
//   wave1: stage OBA, barrier+g, S1O -> G2O -> ROA -> ROB -> CAT 16..31
//   __syncthreads (CAT handoff), then wave1: PSI1 -> PSI2 -> epilogue.
// R13 changes vs R12 (151 us session best):
//   * __launch_bounds__(256, 4): VGPR cap 128 (was implicitly squeezed to 60;
//     LDS limits occupancy anyway, measured avg resident waves ~11/CU).
//   * S1N/S1O A-fragments pre-staged in LDS as packed f16 tiles (NBA/OBA),
//     built once per group with coalesced loads + cvt_pkrtz; inner loops are
//     now ds_read_b64/b32 + MFMA + relu-acc only (no per-iter global loads,
//     no per-iter packing).
// A-frag: A[m=lane&15][k=(lane>>4)*8+j]; B-frag: B[k=(lane>>4)*8+j][n=lane&15]
// C/D: col=lane&15, row=(lane>>4)*4+reg.  (HW-verified R7..R12)
// Wave-private LDS uses soft fences (R11-proven); cross-wave CAT uses the
// hardware barrier. nb = 131072 = 16*8192 rows -> 4096 full blocks, no
// partial groups (barrier safe).
// ---------------------------------------------------------------------------

typedef __attribute__((ext_vector_type(8))) _Float16 f16x8;
typedef __attribute__((ext_vector_type(2))) __fp16 fp16x2;
typedef __attribute__((ext_vector_type(4))) float f32x4;

#define XW 85     // floats per input row

// ---- B-frag table in d_ws: 34 frags x 64 lanes x 8 f16 ----
#define FR_S1N  0
#define FR_S1O  4
#define FR_G2N  8
#define FR_G2O  10
#define FR_RNA  12
#define FR_RNB  16
#define FR_ROA  18
#define FR_ROB  22
#define FR_PSI1 24
#define FR_PSI2 32
#define N_FRAGS 34

// ---- per-GROUP LDS layout (bytes); 2 groups per 256-thread block ----
#define BIG_STR 144
#define PHI_STR 80
#define CAT_STR 144
#define L_BIGN 0        // 2304  (wave0 private)
#define L_BIGO 2304     // 2304  (wave1 private; reused for h3)
#define L_PHN  4608     // 1280  (wave0 private)
#define L_PHO  5888     // 1280  (wave1 private)
#define L_CAT  7168     // 2304  (cross-wave, barrier-protected)
#define L_OUT  9472     // 128
#define L_BAR  9600     // 128
#define L_NBA  9728     // 2176 = 16 nbr tiles x 136 B (wave0 private)
#define NBA_STR 136     //   [mm][row m] -> NBA + mm*136 + m*8 (4 f16 = 8 B)
#define L_OBA  11904    // 544 = 8 obst tiles x 68 B (wave1 private)
#define OBA_STR 68      //   [oo][row m] -> OBA + oo*68 + m*4 (2 f16 = 4 B)
#define GRP_LDS 12448   // x2 groups = 24896 B/block -> 6 blk/CU (24 waves)

__device__ __forceinline__ float fast_rcp(float x)  { return __builtin_amdgcn_rcpf(x); }
__device__ __forceinline__ float fast_sqrt(float x) { return __builtin_amdgcn_sqrtf(x); }

__device__ __forceinline__ float two_tanh(float a) {
    float ax = fabsf(a);
    float e = __expf(2.0f * ax);
    float t = 1.0f - 2.0f * fast_rcp(e + 1.0f);
    return copysignf(2.0f * t, a);
}

// Compiler-only ordering barrier for wave-private LDS (R11-proven safe).
__device__ __forceinline__ void lds_order() {
    __asm__ __volatile__("" ::: "memory");
}

__device__ __forceinline__ unsigned pk2(float a, float b) {
    union { fp16x2 h; unsigned u; } t;
    t.h = __builtin_amdgcn_cvt_pkrtz(a, b);
    return t.u;
}
__device__ __forceinline__ f16x8 lds_af(const char* area, int stride, int off, int lane) {
    int mm = lane & 15, qq = lane >> 4;
    return *(const f16x8*)(area + mm * stride + off + qq * 16);
}
__device__ __forceinline__ f16x8 load_bh(const _Float16* wsf, int frag, int lane) {
    return ((const f16x8*)(wsf + (size_t)frag * 512))[lane];
}
__device__ __forceinline__ f32x4 cinit(float b) {
    f32x4 c; c[0] = b; c[1] = b; c[2] = b; c[3] = b; return c;
}
__device__ __forceinline__ f32x4 mfma1(f16x8 a, f16x8 b, f32x4 c) {
    return __builtin_amdgcn_mfma_f32_16x16x32_f16(a, b, c, 0, 0, 0);
}

// ---------------------------------------------------------------------------
// prep: pack weights into f16 B-frag blocks, zero outside (K,N). (unchanged)
// ---------------------------------------------------------------------------
__global__ void bn_prep(const float* __restrict__ Wp1n, const float* __restrict__ Wp2n,
                        const float* __restrict__ Wr1n, const float* __restrict__ Wr2n,
                        const float* __restrict__ Wp1o, const float* __restrict__ Wp2o,
                        const float* __restrict__ Wr1o, const float* __restrict__ Wr2o,
                        const float* __restrict__ Wpsi1, const float* __restrict__ Wpsi2,
                        _Float16* __restrict__ wsf)
{
    int f = blockIdx.x;
    int lane = threadIdx.x;   // 64
    const float* W; int K, N, kk = 0, nt = 0, rel;
    if (f < 4)        { W = Wp1n;  K = 4;  N = 64; nt = f; }
    else if (f < 8)   { W = Wp1o;  K = 2;  N = 64; nt = f - 4; }
    else if (f < 10)  { W = Wp2n;  K = 64; N = 16; kk = f - 8; }
    else if (f < 12)  { W = Wp2o;  K = 64; N = 16; kk = f - 10; }
    else if (f < 16)  { W = Wr1n;  K = 16; N = 64; nt = f - 12; }
    else if (f < 18)  { W = Wr2n;  K = 64; N = 16; kk = f - 16; }
    else if (f < 22)  { W = Wr1o;  K = 16; N = 64; nt = f - 18; }
    else if (f < 24)  { W = Wr2o;  K = 64; N = 16; kk = f - 22; }
    else if (f < 32)  { rel = f - 24; W = Wpsi1; K = 36; N = 64; kk = rel >> 2; nt = rel & 3; }
    else              { W = Wpsi2; K = 64; N = 2;  kk = f - 32; }

    int q = lane >> 4, c = lane & 15;
    _Float16* dst = wsf + (size_t)f * 512 + lane * 8;
    for (int j = 0; j < 8; ++j) {
        int k = kk * 32 + q * 8 + j;
        int n = nt * 16 + c;
        float v = (k < K && n < N) ? W[k * N + n] : 0.f;
        dst[j] = (_Float16)v;
    }
}

// ---------------------------------------------------------------------------
// main: 2 waves per 16-row group; block 256 = 4 waves = 2 groups.
// ---------------------------------------------------------------------------
__global__ __launch_bounds__(256, 4) void bn_main(
    const float* __restrict__ x, const _Float16* __restrict__ wsf,
    const float* __restrict__ bp1n, const float* __restrict__ bp2n,
    const float* __restrict__ br1n, const float* __restrict__ br2n,
    const float* __restrict__ bp1o, const float* __restrict__ bp2o,
    const float* __restrict__ br1o, const float* __restrict__ br2o,
    const float* __restrict__ bpsi1, const float* __restrict__ bpsi2,
    float* __restrict__ out, int nb)
{
    __shared__ char smem[2 * GRP_LDS];
    const int lane = threadIdx.x & 63;
    const int wid  = threadIdx.x >> 6;
    const int grp  = wid >> 1;          // group within block (0..1)
    const int role = wid & 1;           // 0 = neighbor chain, 1 = obstacle+psi
    const int group = blockIdx.x * 2 + grp;
    const int row0 = group * 16;        // nb is an exact multiple of 16*2

    char* Gl   = smem + grp * GRP_LDS;
    char* BIGN = Gl + L_BIGN;
    char* BIGO = Gl + L_BIGO;
    char* PHN  = Gl + L_PHN;
    char* PHO  = Gl + L_PHO;
    char* CAT  = Gl + L_CAT;
    char* OUTA = Gl + L_OUT;
    char* BAR  = Gl + L_BAR;
    char* NBA  = Gl + L_NBA;
    char* OBA  = Gl + L_OBA;

    const int m = lane & 15, q = lane >> 4, c = m;
    const float* xg   = x + (size_t)row0 * XW;         // group base
    const float* xrow = xg + (size_t)m * XW;           // this lane's batch row

    if (role == 0) {
        // =================== WAVE 0: neighbor chain =========================
        // ---- stage neighbor features -> NBA as packed f16 A-tiles ----
        // pair p = t*64+lane over 512 pairs; row = p>>5, pr = p&31,
        // mm = pr>>1, fp = pr&1. Coalesced dword loads, one cvt_pkrtz each.
        {
            int ln5 = lane >> 5;                 // 0/1
            int pr  = lane & 31;
            int mm0 = pr >> 1, fp = pr & 1;
            char* db = NBA + mm0 * NBA_STR + fp * 4;
            const float* s0 = xg + (size_t)ln5 * XW + 5 + pr * 2;
            #pragma unroll
            for (int t = 0; t < 8; ++t) {
                const float* s = s0 + (size_t)(2 * t) * XW;
                *(unsigned*)(db + (2 * t + ln5) * 8) = pk2(s[0], s[1]);
            }
        }

        // zero PHN junk (bytes 32..63 per row)
        for (int i = lane; i < 128; i += 64) {
            int r = i >> 3, d = i & 7;
            *(unsigned*)(PHN + r * PHI_STR + 32 + d * 4) = 0;
        }
        lds_order();

        float b_s1n[4], b_rna[4];
        #pragma unroll
        for (int nt = 0; nt < 4; ++nt) {
            b_s1n[nt] = bp1n[nt * 16 + c];
            b_rna[nt] = br1n[nt * 16 + c];
        }
        float b_g2n = 16.f * bp2n[c];
        float b_rnb = br2n[c];

        f16x8 Bs1n[4], Bg2n[2];
        #pragma unroll
        for (int nt = 0; nt < 4; ++nt) Bs1n[nt] = load_bh(wsf, FR_S1N + nt, lane);
        Bg2n[0] = load_bh(wsf, FR_G2N + 0, lane);
        Bg2n[1] = load_bh(wsf, FR_G2N + 1, lane);

        // S1N: rows-on-M, iterate neighbors, register relu-accumulation.
        // A-frag from NBA: lo 8B = 4 features (k=0..3), hi zeroed; q-lanes
        // broadcast (k>=4 rows of B are zero -> don't-care).
        {
            const int m8 = m * 8;
            f32x4 acc[4];
            #pragma unroll
            for (int nt = 0; nt < 4; ++nt) acc[nt] = cinit(0.f);
            #pragma unroll 8
            for (int mm = 0; mm < 16; ++mm) {
                union { f16x8 v; unsigned u[4]; uint2 h[2]; } A;
                A.h[0] = *(const uint2*)(NBA + mm * NBA_STR + m8);
                A.u[2] = 0; A.u[3] = 0;
                #pragma unroll
                for (int nt = 0; nt < 4; ++nt) {
                    f32x4 cc = mfma1(A.v, Bs1n[nt], cinit(b_s1n[nt]));
                    #pragma unroll
                    for (int reg = 0; reg < 4; ++reg)
                        acc[nt][reg] += fmaxf(cc[reg], 0.f);
                }
            }
            #pragma unroll
            for (int nt = 0; nt < 4; ++nt)
                #pragma unroll
                for (int reg = 0; reg < 4; ++reg)
                    *(_Float16*)(BIGN + (q * 4 + reg) * BIG_STR + (nt * 16 + c) * 2)
                        = (_Float16)acc[nt][reg];
        }
        f16x8 Brna[4];
        #pragma unroll
        for (int nt = 0; nt < 4; ++nt) Brna[nt] = load_bh(wsf, FR_RNA + nt, lane);
        lds_order();

        // G2N -> PHN
        {
            f16x8 A0 = lds_af(BIGN, BIG_STR, 0, lane);
            f16x8 A1 = lds_af(BIGN, BIG_STR, 64, lane);
            f32x4 ca = mfma1(A0, Bg2n[0], cinit(b_g2n));
            f32x4 cb = mfma1(A1, Bg2n[1], cinit(0.f));
            #pragma unroll
            for (int reg = 0; reg < 4; ++reg)
                *(_Float16*)(PHN + (q * 4 + reg) * PHI_STR + c * 2) = (_Float16)(ca[reg] + cb[reg]);
        }
        f16x8 Brnb[2];
        Brnb[0] = load_bh(wsf, FR_RNB + 0, lane);
        Brnb[1] = load_bh(wsf, FR_RNB + 1, lane);
        lds_order();

        // RNA -> BIGN
        {
            f16x8 A = lds_af(PHN, PHI_STR, 0, lane);
            #pragma unroll
            for (int nt = 0; nt < 4; ++nt) {
                f32x4 cc = mfma1(A, Brna[nt], cinit(b_rna[nt]));
                #pragma unroll
                for (int reg = 0; reg < 4; ++reg)
                    *(_Float16*)(BIGN + (q * 4 + reg) * BIG_STR + (nt * 16 + c) * 2) = (_Float16)fmaxf(cc[reg], 0.f);
            }
        }
        lds_order();

        // RNB -> CAT cols 0..15
        {
            f16x8 A0 = lds_af(BIGN, BIG_STR, 0, lane);
            f16x8 A1 = lds_af(BIGN, BIG_STR, 64, lane);
            f32x4 ca = mfma1(A0, Brnb[0], cinit(b_rnb));
            f32x4 cb = mfma1(A1, Brnb[1], cinit(0.f));
            #pragma unroll
            for (int reg = 0; reg < 4; ++reg)
                *(_Float16*)(CAT + (q * 4 + reg) * CAT_STR + c * 2) = (_Float16)(ca[reg] + cb[reg]);
        }
    } else {
        // =================== WAVE 1: obstacle chain + barrier + g ===========
        // ---- stage obstacle features -> OBA as packed f16 A-tiles ----
        // pair p = t*64+lane over 128 pairs; row = p>>3, oo = p&7.
        {
            int r8 = lane >> 3;                  // 0..7
            int oo = lane & 7;
            char* db = OBA + oo * OBA_STR;
            const float* s0 = xg + (size_t)r8 * XW + 69 + oo * 2;
            #pragma unroll
            for (int t = 0; t < 2; ++t) {
                const float* s = s0 + (size_t)(8 * t) * XW;
                *(unsigned*)(db + (8 * t + r8) * 4) = pk2(s[0], s[1]);
            }
        }

        // zero PHO junk + CAT bytes 64..127 (k=32..63 zone; g overwrites 64..71)
        for (int i = lane; i < 128; i += 64) {
            int r = i >> 3, d = i & 7;
            *(unsigned*)(PHO + r * PHI_STR + 32 + d * 4) = 0;
        }
        for (int i = lane; i < 256; i += 64) {
            int r = i >> 4, d = i & 15;
            *(unsigned*)(CAT + r * CAT_STR + 64 + d * 4) = 0;
        }
        lds_order();

        // g -> CAT k=32..35 (after zeros, same wave -> DS in-order)
        if (lane < 16) {
            const float* xr = x + (size_t)(row0 + lane) * XW;
            uint2 gv;
            gv.x = pk2(xr[1], xr[2]);
            gv.y = pk2(xr[3], xr[4]);
            *(uint2*)(CAT + lane * CAT_STR + 64) = gv;
        }

        // barrier terms: lane (row=m, quad q): nbrs 4q..4q+3, obs 2q..2q+1
        {
            float bx = 0.f, by = 0.f;
            #pragma unroll
            for (int i = 0; i < 4; ++i) {
                int n = 4 * q + i;
                float px = -xrow[5 + 4 * n], py = -xrow[6 + 4 * n];
                float nrm = fast_sqrt(px * px + py * py);
                float coef = 0.05f * fast_rcp(nrm * (nrm - 0.3f));
                bx = fmaf(coef, px, bx);
                by = fmaf(coef, py, by);
            }
            #pragma unroll
            for (int i = 0; i < 2; ++i) {
                int o = 2 * q + i;
                float px = -xrow[69 + 2 * o], py = -xrow[70 + 2 * o];
                float nrm = fast_sqrt(px * px + py * py);
                float coef = 0.05f * fast_rcp(nrm * (nrm - 0.3f));
                bx = fmaf(coef, px, bx);
                by = fmaf(coef, py, by);
            }
            bx += __shfl_xor(bx, 16); by += __shfl_xor(by, 16);
            bx += __shfl_xor(bx, 32); by += __shfl_xor(by, 32);
            if (q == 0) { float2 bb; bb.x = bx; bb.y = by; *(float2*)(BAR + m * 8) = bb; }
        }

        float b_s1o[4], b_roa[4];
        #pragma unroll
        for (int nt = 0; nt < 4; ++nt) {
            b_s1o[nt] = bp1o[nt * 16 + c];
            b_roa[nt] = br1o[nt * 16 + c];
        }
        float b_g2o = 8.f * bp2o[c];
        float b_rob = br2o[c];

        f16x8 Bs1o[4], Bg2o[2];
        #pragma unroll
        for (int nt = 0; nt < 4; ++nt) Bs1o[nt] = load_bh(wsf, FR_S1O + nt, lane);
        Bg2o[0] = load_bh(wsf, FR_G2O + 0, lane);
        Bg2o[1] = load_bh(wsf, FR_G2O + 1, lane);

        // S1O: rows-on-M, iterate obstacles; A-frag word0 from OBA, rest zero.
        {
            const int m4 = m * 4;
            f32x4 acc[4];
            #pragma unroll
            for (int nt = 0; nt < 4; ++nt) acc[nt] = cinit(0.f);
            #pragma unroll
            for (int oo = 0; oo < 8; ++oo) {
                union { f16x8 v; unsigned u[4]; } A;
                A.u[0] = *(const unsigned*)(OBA + oo * OBA_STR + m4);
                A.u[1] = 0; A.u[2] = 0; A.u[3] = 0;
                #pragma unroll
                for (int nt = 0; nt < 4; ++nt) {
                    f32x4 cc = mfma1(A.v, Bs1o[nt], cinit(b_s1o[nt]));
                    #pragma unroll
                    for (int reg = 0; reg < 4; ++reg)
                        acc[nt][reg] += fmaxf(cc[reg], 0.f);
                }
            }
            #pragma unroll
            for (int nt = 0; nt < 4; ++nt)
                #pragma unroll
                for (int reg = 0; reg < 4; ++reg)
                    *(_Float16*)(BIGO + (q * 4 + reg) * BIG_STR + (nt * 16 + c) * 2)
                        = (_Float16)acc[nt][reg];
        }
        f16x8 Broa[4];
        #pragma unroll
        for (int nt = 0; nt < 4; ++nt) Broa[nt] = load_bh(wsf, FR_ROA + nt, lane);
        lds_order();

        // G2O -> PHO
        {
            f16x8 A0 = lds_af(BIGO, BIG_STR, 0, lane);
            f16x8 A1 = lds_af(BIGO, BIG_STR, 64, lane);
            f32x4 ca = mfma1(A0, Bg2o[0], cinit(b_g2o));
            f32x4 cb = mfma1(A1, Bg2o[1], cinit(0.f));
            #pragma unroll
            for (int reg = 0; reg < 4; ++reg)
                *(_Float16*)(PHO + (q * 4 + reg) * PHI_STR + c * 2) = (_Float16)(ca[reg] + cb[reg]);
        }
        f16x8 Brob[2];
        Brob[0] = load_bh(wsf, FR_ROB + 0, lane);
        Brob[1] = load_bh(wsf, FR_ROB + 1, lane);
        lds_order();

        // ROA -> BIGO
        {
            f16x8 A = lds_af(PHO, PHI_STR, 0, lane);
            #pragma unroll
            for (int nt = 0; nt < 4; ++nt) {
                f32x4 cc = mfma1(A, Broa[nt], cinit(b_roa[nt]));
                #pragma unroll
                for (int reg = 0; reg < 4; ++reg)
                    *(_Float16*)(BIGO + (q * 4 + reg) * BIG_STR + (nt * 16 + c) * 2) = (_Float16)fmaxf(cc[reg], 0.f);
            }
        }
        lds_order();

        // ROB -> CAT cols 16..31
        {
            f16x8 A0 = lds_af(BIGO, BIG_STR, 0, lane);
            f16x8 A1 = lds_af(BIGO, BIG_STR, 64, lane);
            f32x4 ca = mfma1(A0, Brob[0], cinit(b_rob));
            f32x4 cb = mfma1(A1, Brob[1], cinit(0.f));
            #pragma unroll
            for (int reg = 0; reg < 4; ++reg)
                *(_Float16*)(CAT + (q * 4 + reg) * CAT_STR + (16 + c) * 2) = (_Float16)(ca[reg] + cb[reg]);
        }
    }

    // =================== CAT handoff (cross-wave) ==========================
    __syncthreads();

    if (role == 1) {
        float b_p1[4];
        #pragma unroll
        for (int nt = 0; nt < 4; ++nt) b_p1[nt] = bpsi1[nt * 16 + c];
        float b_p2 = (c < 2) ? bpsi2[c] : 0.f;

        f16x8 Bp1a[4], Bp1b[4], Bp2[2];
        #pragma unroll
        for (int nt = 0; nt < 4; ++nt) Bp1a[nt] = load_bh(wsf, FR_PSI1 + nt, lane);
        #pragma unroll
        for (int nt = 0; nt < 4; ++nt) Bp1b[nt] = load_bh(wsf, FR_PSI1 + 4 + nt, lane);
        Bp2[0] = load_bh(wsf, FR_PSI2 + 0, lane);
        Bp2[1] = load_bh(wsf, FR_PSI2 + 1, lane);

        // PSI1 -> BIGO (reused as h3)
        {
            f16x8 A0 = lds_af(CAT, CAT_STR, 0, lane);    // k 0..31
            f16x8 A1 = lds_af(CAT, CAT_STR, 64, lane);   // k 32..63 (36.. zero)
            #pragma unroll
            for (int nt = 0; nt < 4; ++nt) {
                f32x4 ca = mfma1(A0, Bp1a[nt], cinit(b_p1[nt]));
                f32x4 cb = mfma1(A1, Bp1b[nt], cinit(0.f));
                #pragma unroll
                for (int reg = 0; reg < 4; ++reg)
                    *(_Float16*)(BIGO + (q * 4 + reg) * BIG_STR + (nt * 16 + c) * 2) = (_Float16)fmaxf(ca[reg] + cb[reg], 0.f);
            }
        }
        lds_order();

        // PSI2 -> OUT
        {
            f16x8 A0 = lds_af(BIGO, BIG_STR, 0, lane);
            f16x8 A1 = lds_af(BIGO, BIG_STR, 64, lane);
            f32x4 ca = mfma1(A0, Bp2[0], cinit(b_p2));
            f32x4 cb = mfma1(A1, Bp2[1], cinit(0.f));
            if (c < 2) {
                #pragma unroll
                for (int reg = 0; reg < 4; ++reg)
                    *(float*)(OUTA + (q * 4 + reg) * 8 + c * 4) = ca[reg] + cb[reg];
            }
        }
        lds_order();

        // epilogue
        if (lane < 16) {
            float2 a  = *(const float2*)(OUTA + lane * 8);
            float2 bb = *(const float2*)(BAR + lane * 8);
            float a0 = two_tanh(a.x) + bb.x;
            float a1 = two_tanh(a.y) + bb.y;
            float amax = fmaxf(fabsf(a0), fabsf(a1));
            float inv_alpha = fmaxf(amax * 0.5f, 1.0f);
            float rr = fast_rcp(inv_alpha);
            float2 o; o.x = a0 * rr; o.y = a1 * rr;
            *(float2*)(out + (size_t)(row0 + lane) * 2) = o;
        }
    }
}

extern "C" void kernel_launch(void* const* d_in, const int* in_sizes, int n_in,
                              void* d_out, int out_size, void* d_ws, size_t ws_size,
                              hipStream_t stream) {
    const float* x     = (const float*)d_in[0];
    const float* Wp1n  = (const float*)d_in[1];
    const float* bp1n  = (const float*)d_in[2];
    const float* Wp2n  = (const float*)d_in[3];
    const float* bp2n  = (const float*)d_in[4];
    const float* Wr1n  = (const float*)d_in[5];
    const float* br1n  = (const float*)d_in[6];
    const float* Wr2n  = (const float*)d_in[7];
    const float* br2n  = (const float*)d_in[8];
    const float* Wp1o  = (const float*)d_in[9];
    const float* bp1o  = (const float*)d_in[10];
    const float* Wp2o  = (const float*)d_in[11];
    const float* bp2o  = (const float*)d_in[12];
    const float* Wr1o  = (const float*)d_in[13];
    const float* br1o  = (const float*)d_in[14];
    const float* Wr2o  = (const float*)d_in[15];
    const float* br2o  = (const float*)d_in[16];
    const float* Wpsi1 = (const float*)d_in[17];
    const float* bpsi1 = (const float*)d_in[18];
    const float* Wpsi2 = (const float*)d_in[19];
    const float* bpsi2 = (const float*)d_in[20];
    float* out = (float*)d_out;

    int nb = in_sizes[0] / XW;               // 131072
    _Float16* wsf = (_Float16*)d_ws;         // ~34 KB frag table

    bn_prep<<<N_FRAGS, 64, 0, stream>>>(Wp1n, Wp2n, Wr1n, Wr2n,
                                        Wp1o, Wp2o, Wr1o, Wr2o,
                                        Wpsi1, Wpsi2, wsf);

    int groups = (nb + 15) / 16;             // 8192
    int blocks = (groups + 1) / 2;           // 4096 (2 groups per block)
    bn_main<<<blocks, 256, 0, stream>>>(x, wsf,
                                        bp1n, bp2n, br1n, br2n,
                                        bp1o, bp2o, br1o, br2o,
                                        bpsi1, bpsi2, out, nb);
}

// Round 2
// 145.394 us; speedup vs baseline: 1.0367x; 1.0050x over previous
//
#include <hip/hip_runtime.h>
#include <math.h>

// ---------------------------------------------------------------------------
// Barrier_Net, full-f16 MFMA (16x16x32), WAVE-SPLIT pipeline.
// Group = 16 batch rows handled by a PAIR of waves:
//   wave0: stage NBA -> S1N -> G2N -> RNA -> RNB -> CAT cols 0..15
//   wave1: stage OBA, barrier+g, S1O -> G2O -> ROA -> ROB -> CAT 16..31
//   __syncthreads (CAT handoff), then wave1: PSI1 -> PSI2 -> epilogue.
// R14 changes vs R13 (146 us):
//   * NBA aliases BIGN, OBA aliases BIGO (last staging read precedes first
//     BIG write, same wave, in-order DS) -> GRP_LDS 12448 -> 9728 ->
//     19456 B/block -> 8 blocks/CU = 32 waves (full wave-slot occupancy).
//   * __launch_bounds__(256, 8): VGPR cap 64 to actually reach 8 blk/CU.
//   * Biases embedded in spare K-rows of B-frags (S1N k=4, S1O k=2,
//     RNA/ROA k=16, PSI1 k=36) with f16 1.0 planted in the matching A slot
//     (constant A word / LDS pad word). Kills per-lane bias regs + per-MFMA
//     f32x4 bias splats in the hot loops; C-init is one invariant zero vec.
// A-frag: A[m=lane&15][k=(lane>>4)*8+j]; B-frag: B[k=(lane>>4)*8+j][n=lane&15]
// C/D: col=lane&15, row=(lane>>4)*4+reg.  (HW-verified R7..R12)
// Wave-private LDS uses soft fences (R11-proven); cross-wave CAT uses the
// hardware barrier. nb = 131072 = 16*8192 rows -> 4096 full blocks, no
// partial groups (barrier safe).
// ---------------------------------------------------------------------------

typedef __attribute__((ext_vector_type(8))) _Float16 f16x8;
typedef __attribute__((ext_vector_type(2))) __fp16 fp16x2;
typedef __attribute__((ext_vector_type(4))) float f32x4;

#define XW 85     // floats per input row

// ---- B-frag table in d_ws: 34 frags x 64 lanes x 8 f16 ----
#define FR_S1N  0
#define FR_S1O  4
#define FR_G2N  8
#define FR_G2O  10
#define FR_RNA  12
#define FR_RNB  16
#define FR_ROA  18
#define FR_ROB  22
#define FR_PSI1 24
#define FR_PSI2 32
#define N_FRAGS 34

// ---- per-GROUP LDS layout (bytes); 2 groups per 256-thread block ----
#define BIG_STR 144
#define PHI_STR 80
#define CAT_STR 144
#define L_BIGN 0        // 2304  (wave0 private; NBA staging aliases this)
#define L_BIGO 2304     // 2304  (wave1 private; OBA staging aliases; h3 reuse)
#define L_PHN  4608     // 1280  (wave0 private)
#define L_PHO  5888     // 1280  (wave1 private)
#define L_CAT  7168     // 2304  (cross-wave, barrier-protected)
#define L_OUT  9472     // 128
#define L_BAR  9600     // 128
#define GRP_LDS 9728    // x2 groups = 19456 B/block -> 8 blk/CU, 32 waves
#define NBA_STR 136     // staging tile stride inside BIGN region
#define OBA_STR 68      // staging tile stride inside BIGO region

#define H16_ONE 0x00003C00u   // f16 1.0 in low half of a dword

__device__ __forceinline__ float fast_rcp(float x)  { return __builtin_amdgcn_rcpf(x); }
__device__ __forceinline__ float fast_sqrt(float x) { return __builtin_amdgcn_sqrtf(x); }

__device__ __forceinline__ float two_tanh(float a) {
    float ax = fabsf(a);
    float e = __expf(2.0f * ax);
    float t = 1.0f - 2.0f * fast_rcp(e + 1.0f);
    return copysignf(2.0f * t, a);
}

// Compiler-only ordering barrier for wave-private LDS (R11-proven safe).
__device__ __forceinline__ void lds_order() {
    __asm__ __volatile__("" ::: "memory");
}

__device__ __forceinline__ unsigned pk2(float a, float b) {
    union { fp16x2 h; unsigned u; } t;
    t.h = __builtin_amdgcn_cvt_pkrtz(a, b);
    return t.u;
}
__device__ __forceinline__ f16x8 lds_af(const char* area, int stride, int off, int lane) {
    int mm = lane & 15, qq = lane >> 4;
    return *(const f16x8*)(area + mm * stride + off + qq * 16);
}
__device__ __forceinline__ f16x8 load_bh(const _Float16* wsf, int frag, int lane) {
    return ((const f16x8*)(wsf + (size_t)frag * 512))[lane];
}
__device__ __forceinline__ f32x4 cinit(float b) {
    f32x4 c; c[0] = b; c[1] = b; c[2] = b; c[3] = b; return c;
}
__device__ __forceinline__ f32x4 mfma1(f16x8 a, f16x8 b, f32x4 c) {
    return __builtin_amdgcn_mfma_f32_16x16x32_f16(a, b, c, 0, 0, 0);
}

// ---------------------------------------------------------------------------
// prep: pack weights into f16 B-frag blocks, zero outside (K,N).
// R14: bias vector embedded at row K (first spare k-slot) where available.
// ---------------------------------------------------------------------------
__global__ void bn_prep(const float* __restrict__ Wp1n, const float* __restrict__ Wp2n,
                        const float* __restrict__ Wr1n, const float* __restrict__ Wr2n,
                        const float* __restrict__ Wp1o, const float* __restrict__ Wp2o,
                        const float* __restrict__ Wr1o, const float* __restrict__ Wr2o,
                        const float* __restrict__ Wpsi1, const float* __restrict__ Wpsi2,
                        const float* __restrict__ bp1n, const float* __restrict__ bp1o,
                        const float* __restrict__ br1n, const float* __restrict__ br1o,
                        const float* __restrict__ bpsi1,
                        _Float16* __restrict__ wsf)
{
    int f = blockIdx.x;
    int lane = threadIdx.x;   // 64
    const float* W; const float* bias = nullptr;
    int K, N, kk = 0, nt = 0, rel, kbias = -1;
    if (f < 4)        { W = Wp1n;  K = 4;  N = 64; nt = f;      bias = bp1n;  kbias = 4; }
    else if (f < 8)   { W = Wp1o;  K = 2;  N = 64; nt = f - 4;  bias = bp1o;  kbias = 2; }
    else if (f < 10)  { W = Wp2n;  K = 64; N = 16; kk = f - 8; }
    else if (f < 12)  { W = Wp2o;  K = 64; N = 16; kk = f - 10; }
    else if (f < 16)  { W = Wr1n;  K = 16; N = 64; nt = f - 12; bias = br1n;  kbias = 16; }
    else if (f < 18)  { W = Wr2n;  K = 64; N = 16; kk = f - 16; }
    else if (f < 22)  { W = Wr1o;  K = 16; N = 64; nt = f - 18; bias = br1o;  kbias = 16; }
    else if (f < 24)  { W = Wr2o;  K = 64; N = 16; kk = f - 22; }
    else if (f < 32)  { rel = f - 24; W = Wpsi1; K = 36; N = 64; kk = rel >> 2; nt = rel & 3;
                        bias = bpsi1; kbias = 36; }
    else              { W = Wpsi2; K = 64; N = 2;  kk = f - 32; }

    int q = lane >> 4, c = lane & 15;
    _Float16* dst = wsf + (size_t)f * 512 + lane * 8;
    for (int j = 0; j < 8; ++j) {
        int k = kk * 32 + q * 8 + j;
        int n = nt * 16 + c;
        float v = 0.f;
        if (n < N) {
            if (k < K) v = W[k * N + n];
            else if (k == kbias) v = bias[n];
        }
        dst[j] = (_Float16)v;
    }
}

// ---------------------------------------------------------------------------
// main: 2 waves per 16-row group; block 256 = 4 waves = 2 groups.
// ---------------------------------------------------------------------------
__global__ __launch_bounds__(256, 8) void bn_main(
    const float* __restrict__ x, const _Float16* __restrict__ wsf,
    const float* __restrict__ bp2n, const float* __restrict__ br2n,
    const float* __restrict__ bp2o, const float* __restrict__ br2o,
    const float* __restrict__ bpsi2,
    float* __restrict__ out, int nb)
{
    __shared__ char smem[2 * GRP_LDS];
    const int lane = threadIdx.x & 63;
    const int wid  = threadIdx.x >> 6;
    const int grp  = wid >> 1;          // group within block (0..1)
    const int role = wid & 1;           // 0 = neighbor chain, 1 = obstacle+psi
    const int group = blockIdx.x * 2 + grp;
    const int row0 = group * 16;        // nb is an exact multiple of 16*2

    char* Gl   = smem + grp * GRP_LDS;
    char* BIGN = Gl + L_BIGN;
    char* BIGO = Gl + L_BIGO;
    char* PHN  = Gl + L_PHN;
    char* PHO  = Gl + L_PHO;
    char* CAT  = Gl + L_CAT;
    char* OUTA = Gl + L_OUT;
    char* BAR  = Gl + L_BAR;
    char* NBA  = BIGN;                  // staging aliases BIGN (R14)
    char* OBA  = BIGO;                  // staging aliases BIGO (R14)

    const int m = lane & 15, q = lane >> 4, c = m;
    const float* xg   = x + (size_t)row0 * XW;         // group base
    const float* xrow = xg + (size_t)m * XW;           // this lane's batch row

    const f32x4 ZC = cinit(0.f);        // shared zero C-operand (invariant)

    if (role == 0) {
        // =================== WAVE 0: neighbor chain =========================
        // ---- stage neighbor features -> NBA as packed f16 A-tiles ----
        {
            int ln5 = lane >> 5;                 // 0/1
            int pr  = lane & 31;
            int mm0 = pr >> 1, fp = pr & 1;
            char* db = NBA + mm0 * NBA_STR + fp * 4;
            const float* s0 = xg + (size_t)ln5 * XW + 5 + pr * 2;
            #pragma unroll
            for (int t = 0; t < 8; ++t) {
                const float* s = s0 + (size_t)(2 * t) * XW;
                *(unsigned*)(db + (2 * t + ln5) * 8) = pk2(s[0], s[1]);
            }
        }

        // PHN pad: k=16 slot = f16 1.0 (RNA bias row), rest zero
        {
            unsigned zv = ((lane & 7) == 0) ? H16_ONE : 0u;
            for (int i = lane; i < 128; i += 64) {
                int r = i >> 3, d = i & 7;
                *(unsigned*)(PHN + r * PHI_STR + 32 + d * 4) = zv;
            }
        }
        lds_order();

        f16x8 Bs1n[4];
        #pragma unroll
        for (int nt = 0; nt < 4; ++nt) Bs1n[nt] = load_bh(wsf, FR_S1N + nt, lane);

        // S1N: rows-on-M, iterate neighbors, register relu-accumulation.
        // A word2 = f16 1.0 at k=4 (bias row in B); words hoisted.
        {
            const int m8 = m * 8;
            f32x4 acc[4];
            #pragma unroll
            for (int nt = 0; nt < 4; ++nt) acc[nt] = cinit(0.f);
            union { f16x8 v; unsigned u[4]; uint2 h[2]; } A;
            A.u[2] = H16_ONE; A.u[3] = 0;
            #pragma unroll 8
            for (int mm = 0; mm < 16; ++mm) {
                A.h[0] = *(const uint2*)(NBA + mm * NBA_STR + m8);
                #pragma unroll
                for (int nt = 0; nt < 4; ++nt) {
                    f32x4 cc = mfma1(A.v, Bs1n[nt], ZC);
                    #pragma unroll
                    for (int reg = 0; reg < 4; ++reg)
                        acc[nt][reg] += fmaxf(cc[reg], 0.f);
                }
            }
            lds_order();   // NBA reads done; BIGN stores below may alias
            #pragma unroll
            for (int nt = 0; nt < 4; ++nt)
                #pragma unroll
                for (int reg = 0; reg < 4; ++reg)
                    *(_Float16*)(BIGN + (q * 4 + reg) * BIG_STR + (nt * 16 + c) * 2)
                        = (_Float16)acc[nt][reg];
        }
        lds_order();

        // G2N -> PHN
        {
            float b_g2n = 16.f * bp2n[c];
            f16x8 Bg2n0 = load_bh(wsf, FR_G2N + 0, lane);
            f16x8 Bg2n1 = load_bh(wsf, FR_G2N + 1, lane);
            f16x8 A0 = lds_af(BIGN, BIG_STR, 0, lane);
            f16x8 A1 = lds_af(BIGN, BIG_STR, 64, lane);
            f32x4 ca = mfma1(A0, Bg2n0, cinit(b_g2n));
            f32x4 cb = mfma1(A1, Bg2n1, ZC);
            #pragma unroll
            for (int reg = 0; reg < 4; ++reg)
                *(_Float16*)(PHN + (q * 4 + reg) * PHI_STR + c * 2) = (_Float16)(ca[reg] + cb[reg]);
        }
        lds_order();

        // RNA -> BIGN  (bias via k=16 row; A k=16 slot is the 1.0 pad word)
        {
            f16x8 Brna[4];
            #pragma unroll
            for (int nt = 0; nt < 4; ++nt) Brna[nt] = load_bh(wsf, FR_RNA + nt, lane);
            f16x8 A = lds_af(PHN, PHI_STR, 0, lane);
            #pragma unroll
            for (int nt = 0; nt < 4; ++nt) {
                f32x4 cc = mfma1(A, Brna[nt], ZC);
                #pragma unroll
                for (int reg = 0; reg < 4; ++reg)
                    *(_Float16*)(BIGN + (q * 4 + reg) * BIG_STR + (nt * 16 + c) * 2) = (_Float16)fmaxf(cc[reg], 0.f);
            }
        }
        lds_order();

        // RNB -> CAT cols 0..15
        {
            float b_rnb = br2n[c];
            f16x8 Brnb0 = load_bh(wsf, FR_RNB + 0, lane);
            f16x8 Brnb1 = load_bh(wsf, FR_RNB + 1, lane);
            f16x8 A0 = lds_af(BIGN, BIG_STR, 0, lane);
            f16x8 A1 = lds_af(BIGN, BIG_STR, 64, lane);
            f32x4 ca = mfma1(A0, Brnb0, cinit(b_rnb));
            f32x4 cb = mfma1(A1, Brnb1, ZC);
            #pragma unroll
            for (int reg = 0; reg < 4; ++reg)
                *(_Float16*)(CAT + (q * 4 + reg) * CAT_STR + c * 2) = (_Float16)(ca[reg] + cb[reg]);
        }
    } else {
        // =================== WAVE 1: obstacle chain + barrier + g ===========
        // ---- stage obstacle features -> OBA as packed f16 A-tiles ----
        {
            int r8 = lane >> 3;                  // 0..7
            int oo = lane & 7;
            char* db = OBA + oo * OBA_STR;
            const float* s0 = xg + (size_t)r8 * XW + 69 + oo * 2;
            #pragma unroll
            for (int t = 0; t < 2; ++t) {
                const float* s = s0 + (size_t)(8 * t) * XW;
                *(unsigned*)(db + (8 * t + r8) * 4) = pk2(s[0], s[1]);
            }
        }

        // PHO pad: k=16 slot = f16 1.0 (ROA bias row), rest zero
        {
            unsigned zv = ((lane & 7) == 0) ? H16_ONE : 0u;
            for (int i = lane; i < 128; i += 64) {
                int r = i >> 3, d = i & 7;
                *(unsigned*)(PHO + r * PHI_STR + 32 + d * 4) = zv;
            }
        }
        // CAT k=32..63 zone: k=36 slot = f16 1.0 (PSI1 bias row), rest zero;
        // g overwrites k=32..35 (bytes 64..71) below.
        {
            unsigned zc = ((lane & 15) == 2) ? H16_ONE : 0u;
            for (int i = lane; i < 256; i += 64) {
                int r = i >> 4, d = i & 15;
                *(unsigned*)(CAT + r * CAT_STR + 64 + d * 4) = zc;
            }
        }
        lds_order();

        // g -> CAT k=32..35 (after zeros, same wave -> DS in-order)
        if (lane < 16) {
            const float* xr = x + (size_t)(row0 + lane) * XW;
            uint2 gv;
            gv.x = pk2(xr[1], xr[2]);
            gv.y = pk2(xr[3], xr[4]);
            *(uint2*)(CAT + lane * CAT_STR + 64) = gv;
        }

        // barrier terms: lane (row=m, quad q): nbrs 4q..4q+3, obs 2q..2q+1
        {
            float bx = 0.f, by = 0.f;
            #pragma unroll
            for (int i = 0; i < 4; ++i) {
                int n = 4 * q + i;
                float px = -xrow[5 + 4 * n], py = -xrow[6 + 4 * n];
                float nrm = fast_sqrt(px * px + py * py);
                float coef = 0.05f * fast_rcp(nrm * (nrm - 0.3f));
                bx = fmaf(coef, px, bx);
                by = fmaf(coef, py, by);
            }
            #pragma unroll
            for (int i = 0; i < 2; ++i) {
                int o = 2 * q + i;
                float px = -xrow[69 + 2 * o], py = -xrow[70 + 2 * o];
                float nrm = fast_sqrt(px * px + py * py);
                float coef = 0.05f * fast_rcp(nrm * (nrm - 0.3f));
                bx = fmaf(coef, px, bx);
                by = fmaf(coef, py, by);
            }
            bx += __shfl_xor(bx, 16); by += __shfl_xor(by, 16);
            bx += __shfl_xor(bx, 32); by += __shfl_xor(by, 32);
            if (q == 0) { float2 bb; bb.x = bx; bb.y = by; *(float2*)(BAR + m * 8) = bb; }
        }

        f16x8 Bs1o[4];
        #pragma unroll
        for (int nt = 0; nt < 4; ++nt) Bs1o[nt] = load_bh(wsf, FR_S1O + nt, lane);

        // S1O: rows-on-M, iterate obstacles; A word1 = f16 1.0 at k=2 (bias).
        {
            const int m4 = m * 4;
            f32x4 acc[4];
            #pragma unroll
            for (int nt = 0; nt < 4; ++nt) acc[nt] = cinit(0.f);
            union { f16x8 v; unsigned u[4]; } A;
            A.u[1] = H16_ONE; A.u[2] = 0; A.u[3] = 0;
            #pragma unroll
            for (int oo = 0; oo < 8; ++oo) {
                A.u[0] = *(const unsigned*)(OBA + oo * OBA_STR + m4);
                #pragma unroll
                for (int nt = 0; nt < 4; ++nt) {
                    f32x4 cc = mfma1(A.v, Bs1o[nt], ZC);
                    #pragma unroll
                    for (int reg = 0; reg < 4; ++reg)
                        acc[nt][reg] += fmaxf(cc[reg], 0.f);
                }
            }
            lds_order();   // OBA reads done; BIGO stores below may alias
            #pragma unroll
            for (int nt = 0; nt < 4; ++nt)
                #pragma unroll
                for (int reg = 0; reg < 4; ++reg)
                    *(_Float16*)(BIGO + (q * 4 + reg) * BIG_STR + (nt * 16 + c) * 2)
                        = (_Float16)acc[nt][reg];
        }
        lds_order();

        // G2O -> PHO
        {
            float b_g2o = 8.f * bp2o[c];
            f16x8 Bg2o0 = load_bh(wsf, FR_G2O + 0, lane);
            f16x8 Bg2o1 = load_bh(wsf, FR_G2O + 1, lane);
            f16x8 A0 = lds_af(BIGO, BIG_STR, 0, lane);
            f16x8 A1 = lds_af(BIGO, BIG_STR, 64, lane);
            f32x4 ca = mfma1(A0, Bg2o0, cinit(b_g2o));
            f32x4 cb = mfma1(A1, Bg2o1, ZC);
            #pragma unroll
            for (int reg = 0; reg < 4; ++reg)
                *(_Float16*)(PHO + (q * 4 + reg) * PHI_STR + c * 2) = (_Float16)(ca[reg] + cb[reg]);
        }
        lds_order();

        // ROA -> BIGO  (bias via k=16 row; A k=16 slot is the 1.0 pad word)
        {
            f16x8 Broa[4];
            #pragma unroll
            for (int nt = 0; nt < 4; ++nt) Broa[nt] = load_bh(wsf, FR_ROA + nt, lane);
            f16x8 A = lds_af(PHO, PHI_STR, 0, lane);
            #pragma unroll
            for (int nt = 0; nt < 4; ++nt) {
                f32x4 cc = mfma1(A, Broa[nt], ZC);
                #pragma unroll
                for (int reg = 0; reg < 4; ++reg)
                    *(_Float16*)(BIGO + (q * 4 + reg) * BIG_STR + (nt * 16 + c) * 2) = (_Float16)fmaxf(cc[reg], 0.f);
            }
        }
        lds_order();

        // ROB -> CAT cols 16..31
        {
            float b_rob = br2o[c];
            f16x8 Brob0 = load_bh(wsf, FR_ROB + 0, lane);
            f16x8 Brob1 = load_bh(wsf, FR_ROB + 1, lane);
            f16x8 A0 = lds_af(BIGO, BIG_STR, 0, lane);
            f16x8 A1 = lds_af(BIGO, BIG_STR, 64, lane);
            f32x4 ca = mfma1(A0, Brob0, cinit(b_rob));
            f32x4 cb = mfma1(A1, Brob1, ZC);
            #pragma unroll
            for (int reg = 0; reg < 4; ++reg)
                *(_Float16*)(CAT + (q * 4 + reg) * CAT_STR + (16 + c) * 2) = (_Float16)(ca[reg] + cb[reg]);
        }
    }

    // =================== CAT handoff (cross-wave) ==========================
    __syncthreads();

    if (role == 1) {
        f16x8 Bp1a[4], Bp1b[4], Bp2[2];
        #pragma unroll
        for (int nt = 0; nt < 4; ++nt) Bp1a[nt] = load_bh(wsf, FR_PSI1 + nt, lane);
        #pragma unroll
        for (int nt = 0; nt < 4; ++nt) Bp1b[nt] = load_bh(wsf, FR_PSI1 + 4 + nt, lane);
        Bp2[0] = load_bh(wsf, FR_PSI2 + 0, lane);
        Bp2[1] = load_bh(wsf, FR_PSI2 + 1, lane);

        // PSI1 -> BIGO (reused as h3); bias via k=36 row (1.0 in CAT pad)
        {
            f16x8 A0 = lds_af(CAT, CAT_STR, 0, lane);    // k 0..31
            f16x8 A1 = lds_af(CAT, CAT_STR, 64, lane);   // k 32..63
            #pragma unroll
            for (int nt = 0; nt < 4; ++nt) {
                f32x4 ca = mfma1(A0, Bp1a[nt], ZC);
                f32x4 cb = mfma1(A1, Bp1b[nt], ZC);
                #pragma unroll
                for (int reg = 0; reg < 4; ++reg)
                    *(_Float16*)(BIGO + (q * 4 + reg) * BIG_STR + (nt * 16 + c) * 2) = (_Float16)fmaxf(ca[reg] + cb[reg], 0.f);
            }
        }
        lds_order();

        // PSI2 -> OUT
        {
            float b_p2 = (c < 2) ? bpsi2[c] : 0.f;
            f16x8 A0 = lds_af(BIGO, BIG_STR, 0, lane);
            f16x8 A1 = lds_af(BIGO, BIG_STR, 64, lane);
            f32x4 ca = mfma1(A0, Bp2[0], cinit(b_p2));
            f32x4 cb = mfma1(A1, Bp2[1], ZC);
            if (c < 2) {
                #pragma unroll
                for (int reg = 0; reg < 4; ++reg)
                    *(float*)(OUTA + (q * 4 + reg) * 8 + c * 4) = ca[reg] + cb[reg];
            }
        }
        lds_order();

        // epilogue
        if (lane < 16) {
            float2 a  = *(const float2*)(OUTA + lane * 8);
            float2 bb = *(const float2*)(BAR + lane * 8);
            float a0 = two_tanh(a.x) + bb.x;
            float a1 = two_tanh(a.y) + bb.y;
            float amax = fmaxf(fabsf(a0), fabsf(a1));
            float inv_alpha = fmaxf(amax * 0.5f, 1.0f);
            float rr = fast_rcp(inv_alpha);
            float2 o; o.x = a0 * rr; o.y = a1 * rr;
            *(float2*)(out + (size_t)(row0 + lane) * 2) = o;
        }
    }
}

extern "C" void kernel_launch(void* const* d_in, const int* in_sizes, int n_in,
                              void* d_out, int out_size, void* d_ws, size_t ws_size,
                              hipStream_t stream) {
    const float* x     = (const float*)d_in[0];
    const float* Wp1n  = (const float*)d_in[1];
    const float* bp1n  = (const float*)d_in[2];
    const float* Wp2n  = (const float*)d_in[3];
    const float* bp2n  = (const float*)d_in[4];
    const float* Wr1n  = (const float*)d_in[5];
    const float* br1n  = (const float*)d_in[6];
    const float* Wr2n  = (const float*)d_in[7];
    const float* br2n  = (const float*)d_in[8];
    const float* Wp1o  = (const float*)d_in[9];
    const float* bp1o  = (const float*)d_in[10];
    const float* Wp2o  = (const float*)d_in[11];
    const float* bp2o  = (const float*)d_in[12];
    const float* Wr1o  = (const float*)d_in[13];
    const float* br1o  = (const float*)d_in[14];
    const float* Wr2o  = (const float*)d_in[15];
    const float* br2o  = (const float*)d_in[16];
    const float* Wpsi1 = (const float*)d_in[17];
    const float* bpsi1 = (const float*)d_in[18];
    const float* Wpsi2 = (const float*)d_in[19];
    const float* bpsi2 = (const float*)d_in[20];
    float* out = (float*)d_out;

    int nb = in_sizes[0] / XW;               // 131072
    _Float16* wsf = (_Float16*)d_ws;         // ~34 KB frag table

    bn_prep<<<N_FRAGS, 64, 0, stream>>>(Wp1n, Wp2n, Wr1n, Wr2n,
                                        Wp1o, Wp2o, Wr1o, Wr2o,
                                        Wpsi1, Wpsi2,
                                        bp1n, bp1o, br1n, br1o, bpsi1,
                                        wsf);

    int groups = (nb + 15) / 16;             // 8192
    int blocks = (groups + 1) / 2;           // 4096 (2 groups per block)
    bn_main<<<blocks, 256, 0, stream>>>(x, wsf,
                                        bp2n, br2n, bp2o, br2o, bpsi2,
                                        out, nb);
}

// Round 3
// 145.298 us; speedup vs baseline: 1.0374x; 1.0007x over previous
//
#include <hip/hip_runtime.h>
#include <math.h>

// ---------------------------------------------------------------------------
// Barrier_Net, full-f16 MFMA (16x16x32), SINGLE-WAVE-PER-GROUP pipeline (R15).
// One wave handles 16 batch rows END-TO-END:
//   stage NBA, stage OBA, barrier terms, pads+g,
//   S1N -> G2N -> RNA -> RNB -> CAT[0:15],
//   S1O -> G2O -> ROA -> ROB -> CAT[16:31],
//   PSI1 -> PSI2 -> epilogue.
// NO __syncthreads at all: every LDS region is wave-private; ordering via
// compiler-only lds_order() fences (R11-proven). Removes the R12-R14
// wave-split's CAT-handoff barrier drain and the wave0/wave1 imbalance idle
// (16-nbr chain vs 8-obst chain + lone PSI tail) — the suspected cause of
// R14's neutral result at full occupancy.
// LDS reuse timeline (per group, all wave-private):
//   BIG: NBA staging -> h1n -> h1o -> h3     PHI: phn -> pho (pad written once)
//   CAT: RNB cols0..15, ROB cols16..31, hi-zone pad+g -> PSI1 A-operand
//   OBA: separate 544 B (read at S1O, long after staging)
// 6688 B/group x 4 groups/block = 26752 B -> 6 blocks/CU = 24 independent
// waves/CU. __launch_bounds__(256,6) -> VGPR cap 85 (live set ~70).
// A-frag: A[m=lane&15][k=(lane>>4)*8+j]; B-frag: B[k=(lane>>4)*8+j][n=lane&15]
// C/D: col=lane&15, row=(lane>>4)*4+reg.  (HW-verified R7..R12)
// Biases embedded in spare K-rows of B-frags (R14): S1N k=4, S1O k=2,
// RNA/ROA k=16 (PHI pad 1.0), PSI1 k=36 (CAT pad 1.0).
// nb = 131072 = 64*2048 -> 2048 full blocks, no partial groups.
// ---------------------------------------------------------------------------

typedef __attribute__((ext_vector_type(8))) _Float16 f16x8;
typedef __attribute__((ext_vector_type(2))) __fp16 fp16x2;
typedef __attribute__((ext_vector_type(4))) float f32x4;

#define XW 85     // floats per input row

// ---- B-frag table in d_ws: 34 frags x 64 lanes x 8 f16 ----
#define FR_S1N  0
#define FR_S1O  4
#define FR_G2N  8
#define FR_G2O  10
#define FR_RNA  12
#define FR_RNB  16
#define FR_ROA  18
#define FR_ROB  22
#define FR_PSI1 24
#define FR_PSI2 32
#define N_FRAGS 34

// ---- per-GROUP LDS layout (bytes); 4 groups (waves) per 256-thread block ----
#define BIG_STR 144
#define PHI_STR 80
#define CAT_STR 144
#define L_BIG  0        // 2304  NBA staging / h1n / h1o / h3
#define L_PHI  2304     // 1280  phn / pho (k=16 bias pad written once)
#define L_CAT  3584     // 2304  concat tile (wave-private now)
#define L_OUT  5888     // 128
#define L_BAR  6016     // 128
#define L_OBA  6144     // 544 = 8 obst tiles x 68 B
#define GRP_LDS 6688    // x4 groups = 26752 B/block -> 6 blk/CU, 24 waves/CU
#define NBA_STR 136     // staging tile stride inside BIG region
#define OBA_STR 68

#define H16_ONE 0x00003C00u   // f16 1.0 in low half of a dword

__device__ __forceinline__ float fast_rcp(float x)  { return __builtin_amdgcn_rcpf(x); }
__device__ __forceinline__ float fast_sqrt(float x) { return __builtin_amdgcn_sqrtf(x); }

__device__ __forceinline__ float two_tanh(float a) {
    float ax = fabsf(a);
    float e = __expf(2.0f * ax);
    float t = 1.0f - 2.0f * fast_rcp(e + 1.0f);
    return copysignf(2.0f * t, a);
}

// Compiler-only ordering barrier for wave-private LDS (R11-proven safe).
__device__ __forceinline__ void lds_order() {
    __asm__ __volatile__("" ::: "memory");
}

__device__ __forceinline__ unsigned pk2(float a, float b) {
    union { fp16x2 h; unsigned u; } t;
    t.h = __builtin_amdgcn_cvt_pkrtz(a, b);
    return t.u;
}
__device__ __forceinline__ f16x8 lds_af(const char* area, int stride, int off, int lane) {
    int mm = lane & 15, qq = lane >> 4;
    return *(const f16x8*)(area + mm * stride + off + qq * 16);
}
__device__ __forceinline__ f16x8 load_bh(const _Float16* wsf, int frag, int lane) {
    return ((const f16x8*)(wsf + (size_t)frag * 512))[lane];
}
__device__ __forceinline__ f32x4 cinit(float b) {
    f32x4 c; c[0] = b; c[1] = b; c[2] = b; c[3] = b; return c;
}
__device__ __forceinline__ f32x4 mfma1(f16x8 a, f16x8 b, f32x4 c) {
    return __builtin_amdgcn_mfma_f32_16x16x32_f16(a, b, c, 0, 0, 0);
}

// ---------------------------------------------------------------------------
// prep: pack weights into f16 B-frag blocks, zero outside (K,N).
// Bias vector embedded at row K (first spare k-slot) where applicable (R14).
// ---------------------------------------------------------------------------
__global__ void bn_prep(const float* __restrict__ Wp1n, const float* __restrict__ Wp2n,
                        const float* __restrict__ Wr1n, const float* __restrict__ Wr2n,
                        const float* __restrict__ Wp1o, const float* __restrict__ Wp2o,
                        const float* __restrict__ Wr1o, const float* __restrict__ Wr2o,
                        const float* __restrict__ Wpsi1, const float* __restrict__ Wpsi2,
                        const float* __restrict__ bp1n, const float* __restrict__ bp1o,
                        const float* __restrict__ br1n, const float* __restrict__ br1o,
                        const float* __restrict__ bpsi1,
                        _Float16* __restrict__ wsf)
{
    int f = blockIdx.x;
    int lane = threadIdx.x;   // 64
    const float* W; const float* bias = nullptr;
    int K, N, kk = 0, nt = 0, rel, kbias = -1;
    if (f < 4)        { W = Wp1n;  K = 4;  N = 64; nt = f;      bias = bp1n;  kbias = 4; }
    else if (f < 8)   { W = Wp1o;  K = 2;  N = 64; nt = f - 4;  bias = bp1o;  kbias = 2; }
    else if (f < 10)  { W = Wp2n;  K = 64; N = 16; kk = f - 8; }
    else if (f < 12)  { W = Wp2o;  K = 64; N = 16; kk = f - 10; }
    else if (f < 16)  { W = Wr1n;  K = 16; N = 64; nt = f - 12; bias = br1n;  kbias = 16; }
    else if (f < 18)  { W = Wr2n;  K = 64; N = 16; kk = f - 16; }
    else if (f < 22)  { W = Wr1o;  K = 16; N = 64; nt = f - 18; bias = br1o;  kbias = 16; }
    else if (f < 24)  { W = Wr2o;  K = 64; N = 16; kk = f - 22; }
    else if (f < 32)  { rel = f - 24; W = Wpsi1; K = 36; N = 64; kk = rel >> 2; nt = rel & 3;
                        bias = bpsi1; kbias = 36; }
    else              { W = Wpsi2; K = 64; N = 2;  kk = f - 32; }

    int q = lane >> 4, c = lane & 15;
    _Float16* dst = wsf + (size_t)f * 512 + lane * 8;
    for (int j = 0; j < 8; ++j) {
        int k = kk * 32 + q * 8 + j;
        int n = nt * 16 + c;
        float v = 0.f;
        if (n < N) {
            if (k < K) v = W[k * N + n];
            else if (k == kbias) v = bias[n];
        }
        dst[j] = (_Float16)v;
    }
}

// ---------------------------------------------------------------------------
// main: 1 wave per 16-row group; block 256 = 4 independent waves/groups.
// ---------------------------------------------------------------------------
__global__ __launch_bounds__(256, 6) void bn_main(
    const float* __restrict__ x, const _Float16* __restrict__ wsf,
    const float* __restrict__ bp2n, const float* __restrict__ br2n,
    const float* __restrict__ bp2o, const float* __restrict__ br2o,
    const float* __restrict__ bpsi2,
    float* __restrict__ out, int nb)
{
    __shared__ char smem[4 * GRP_LDS];
    const int lane = threadIdx.x & 63;
    const int wid  = threadIdx.x >> 6;            // 0..3 = group within block
    const int group = blockIdx.x * 4 + wid;
    const int row0 = group * 16;                  // nb is exact multiple of 64

    char* Gl   = smem + wid * GRP_LDS;
    char* BIG  = Gl + L_BIG;
    char* PHI  = Gl + L_PHI;
    char* CAT  = Gl + L_CAT;
    char* OUTA = Gl + L_OUT;
    char* BAR  = Gl + L_BAR;
    char* OBA  = Gl + L_OBA;
    char* NBA  = BIG;                  // staging aliases BIG

    const int m = lane & 15, q = lane >> 4, c = m;
    const float* xg   = x + (size_t)row0 * XW;    // group base
    const float* xrow = xg + (size_t)m * XW;      // this lane's batch row

    const f32x4 ZC = cinit(0.f);       // shared zero C-operand (invariant)

    // ---- stage neighbor features -> NBA (= BIG) as packed f16 A-tiles ----
    {
        int ln5 = lane >> 5;                 // 0/1
        int pr  = lane & 31;
        int mm0 = pr >> 1, fp = pr & 1;
        char* db = NBA + mm0 * NBA_STR + fp * 4;
        const float* s0 = xg + (size_t)ln5 * XW + 5 + pr * 2;
        #pragma unroll
        for (int t = 0; t < 8; ++t) {
            const float* s = s0 + (size_t)(2 * t) * XW;
            *(unsigned*)(db + (2 * t + ln5) * 8) = pk2(s[0], s[1]);
        }
    }
    // ---- stage obstacle features -> OBA (separate region) ----
    {
        int r8 = lane >> 3;                  // 0..7
        int oo = lane & 7;
        char* db = OBA + oo * OBA_STR;
        const float* s0 = xg + (size_t)r8 * XW + 69 + oo * 2;
        #pragma unroll
        for (int t = 0; t < 2; ++t) {
            const float* s = s0 + (size_t)(8 * t) * XW;
            *(unsigned*)(db + (8 * t + r8) * 4) = pk2(s[0], s[1]);
        }
    }

    // ---- PHI pad (serves RNA *and* ROA): k=16 slot = f16 1.0, rest zero ----
    {
        unsigned zv = ((lane & 7) == 0) ? H16_ONE : 0u;
        for (int i = lane; i < 128; i += 64) {
            int r = i >> 3, d = i & 7;
            *(unsigned*)(PHI + r * PHI_STR + 32 + d * 4) = zv;
        }
    }
    // ---- CAT hi-zone (k=32..63): k=36 slot = f16 1.0 (PSI1 bias), rest 0 ----
    {
        unsigned zc = ((lane & 15) == 2) ? H16_ONE : 0u;
        for (int i = lane; i < 256; i += 64) {
            int r = i >> 4, d = i & 15;
            *(unsigned*)(CAT + r * CAT_STR + 64 + d * 4) = zc;
        }
    }
    // ---- g -> CAT k=32..35 (same wave, DS in-order after zeros) ----
    if (lane < 16) {
        const float* xr = x + (size_t)(row0 + lane) * XW;
        uint2 gv;
        gv.x = pk2(xr[1], xr[2]);
        gv.y = pk2(xr[3], xr[4]);
        *(uint2*)(CAT + lane * CAT_STR + 64) = gv;
    }

    // ---- barrier terms: lane (row m, quad q): nbrs 4q..4q+3, obs 2q..2q+1 ----
    {
        float bx = 0.f, by = 0.f;
        #pragma unroll
        for (int i = 0; i < 4; ++i) {
            int n = 4 * q + i;
            float px = -xrow[5 + 4 * n], py = -xrow[6 + 4 * n];
            float nrm = fast_sqrt(px * px + py * py);
            float coef = 0.05f * fast_rcp(nrm * (nrm - 0.3f));
            bx = fmaf(coef, px, bx);
            by = fmaf(coef, py, by);
        }
        #pragma unroll
        for (int i = 0; i < 2; ++i) {
            int o = 2 * q + i;
            float px = -xrow[69 + 2 * o], py = -xrow[70 + 2 * o];
            float nrm = fast_sqrt(px * px + py * py);
            float coef = 0.05f * fast_rcp(nrm * (nrm - 0.3f));
            bx = fmaf(coef, px, bx);
            by = fmaf(coef, py, by);
        }
        bx += __shfl_xor(bx, 16); by += __shfl_xor(by, 16);
        bx += __shfl_xor(bx, 32); by += __shfl_xor(by, 32);
        if (q == 0) { float2 bb; bb.x = bx; bb.y = by; *(float2*)(BAR + m * 8) = bb; }
    }
    lds_order();

    // =================== neighbor chain ====================================
    // S1N: iterate 16 neighbors, register relu-accumulation.
    {
        f16x8 Bs1n[4];
        #pragma unroll
        for (int nt = 0; nt < 4; ++nt) Bs1n[nt] = load_bh(wsf, FR_S1N + nt, lane);

        const int m8 = m * 8;
        f32x4 acc[4];
        #pragma unroll
        for (int nt = 0; nt < 4; ++nt) acc[nt] = cinit(0.f);
        union { f16x8 v; unsigned u[4]; uint2 h[2]; } A;
        A.u[2] = H16_ONE; A.u[3] = 0;        // k=4 bias slot
        #pragma unroll 8
        for (int mm = 0; mm < 16; ++mm) {
            A.h[0] = *(const uint2*)(NBA + mm * NBA_STR + m8);
            #pragma unroll
            for (int nt = 0; nt < 4; ++nt) {
                f32x4 cc = mfma1(A.v, Bs1n[nt], ZC);
                #pragma unroll
                for (int reg = 0; reg < 4; ++reg)
                    acc[nt][reg] += fmaxf(cc[reg], 0.f);
            }
        }
        lds_order();   // NBA reads done; BIG stores below alias it
        #pragma unroll
        for (int nt = 0; nt < 4; ++nt)
            #pragma unroll
            for (int reg = 0; reg < 4; ++reg)
                *(_Float16*)(BIG + (q * 4 + reg) * BIG_STR + (nt * 16 + c) * 2)
                    = (_Float16)acc[nt][reg];
    }
    lds_order();

    // G2N -> PHI (phn)
    {
        float b_g2n = 16.f * bp2n[c];
        f16x8 Bg2n0 = load_bh(wsf, FR_G2N + 0, lane);
        f16x8 Bg2n1 = load_bh(wsf, FR_G2N + 1, lane);
        f16x8 A0 = lds_af(BIG, BIG_STR, 0, lane);
        f16x8 A1 = lds_af(BIG, BIG_STR, 64, lane);
        f32x4 ca = mfma1(A0, Bg2n0, cinit(b_g2n));
        f32x4 cb = mfma1(A1, Bg2n1, ZC);
        #pragma unroll
        for (int reg = 0; reg < 4; ++reg)
            *(_Float16*)(PHI + (q * 4 + reg) * PHI_STR + c * 2) = (_Float16)(ca[reg] + cb[reg]);
    }
    lds_order();

    // RNA -> BIG (bias via k=16 pad row)
    {
        f16x8 Brna[4];
        #pragma unroll
        for (int nt = 0; nt < 4; ++nt) Brna[nt] = load_bh(wsf, FR_RNA + nt, lane);
        f16x8 A = lds_af(PHI, PHI_STR, 0, lane);
        #pragma unroll
        for (int nt = 0; nt < 4; ++nt) {
            f32x4 cc = mfma1(A, Brna[nt], ZC);
            #pragma unroll
            for (int reg = 0; reg < 4; ++reg)
                *(_Float16*)(BIG + (q * 4 + reg) * BIG_STR + (nt * 16 + c) * 2) = (_Float16)fmaxf(cc[reg], 0.f);
        }
    }
    lds_order();

    // RNB -> CAT cols 0..15
    {
        float b_rnb = br2n[c];
        f16x8 Brnb0 = load_bh(wsf, FR_RNB + 0, lane);
        f16x8 Brnb1 = load_bh(wsf, FR_RNB + 1, lane);
        f16x8 A0 = lds_af(BIG, BIG_STR, 0, lane);
        f16x8 A1 = lds_af(BIG, BIG_STR, 64, lane);
        f32x4 ca = mfma1(A0, Brnb0, cinit(b_rnb));
        f32x4 cb = mfma1(A1, Brnb1, ZC);
        #pragma unroll
        for (int reg = 0; reg < 4; ++reg)
            *(_Float16*)(CAT + (q * 4 + reg) * CAT_STR + c * 2) = (_Float16)(ca[reg] + cb[reg]);
    }
    lds_order();

    // =================== obstacle chain ====================================
    // S1O: iterate 8 obstacles (A word1 = f16 1.0 at k=2 bias slot)
    {
        f16x8 Bs1o[4];
        #pragma unroll
        for (int nt = 0; nt < 4; ++nt) Bs1o[nt] = load_bh(wsf, FR_S1O + nt, lane);

        const int m4 = m * 4;
        f32x4 acc[4];
        #pragma unroll
        for (int nt = 0; nt < 4; ++nt) acc[nt] = cinit(0.f);
        union { f16x8 v; unsigned u[4]; } A;
        A.u[1] = H16_ONE; A.u[2] = 0; A.u[3] = 0;
        #pragma unroll
        for (int oo = 0; oo < 8; ++oo) {
            A.u[0] = *(const unsigned*)(OBA + oo * OBA_STR + m4);
            #pragma unroll
            for (int nt = 0; nt < 4; ++nt) {
                f32x4 cc = mfma1(A.v, Bs1o[nt], ZC);
                #pragma unroll
                for (int reg = 0; reg < 4; ++reg)
                    acc[nt][reg] += fmaxf(cc[reg], 0.f);
            }
        }
        lds_order();   // BIG (h1n) reads done (RNB above); safe to overwrite
        #pragma unroll
        for (int nt = 0; nt < 4; ++nt)
            #pragma unroll
            for (int reg = 0; reg < 4; ++reg)
                *(_Float16*)(BIG + (q * 4 + reg) * BIG_STR + (nt * 16 + c) * 2)
                    = (_Float16)acc[nt][reg];
    }
    lds_order();

    // G2O -> PHI (pho; pad row still intact)
    {
        float b_g2o = 8.f * bp2o[c];
        f16x8 Bg2o0 = load_bh(wsf, FR_G2O + 0, lane);
        f16x8 Bg2o1 = load_bh(wsf, FR_G2O + 1, lane);
        f16x8 A0 = lds_af(BIG, BIG_STR, 0, lane);
        f16x8 A1 = lds_af(BIG, BIG_STR, 64, lane);
        f32x4 ca = mfma1(A0, Bg2o0, cinit(b_g2o));
        f32x4 cb = mfma1(A1, Bg2o1, ZC);
        #pragma unroll
        for (int reg = 0; reg < 4; ++reg)
            *(_Float16*)(PHI + (q * 4 + reg) * PHI_STR + c * 2) = (_Float16)(ca[reg] + cb[reg]);
    }
    lds_order();

    // ROA -> BIG (bias via k=16 pad row)
    {
        f16x8 Broa[4];
        #pragma unroll
        for (int nt = 0; nt < 4; ++nt) Broa[nt] = load_bh(wsf, FR_ROA + nt, lane);
        f16x8 A = lds_af(PHI, PHI_STR, 0, lane);
        #pragma unroll
        for (int nt = 0; nt < 4; ++nt) {
            f32x4 cc = mfma1(A, Broa[nt], ZC);
            #pragma unroll
            for (int reg = 0; reg < 4; ++reg)
                *(_Float16*)(BIG + (q * 4 + reg) * BIG_STR + (nt * 16 + c) * 2) = (_Float16)fmaxf(cc[reg], 0.f);
        }
    }
    lds_order();

    // ROB -> CAT cols 16..31
    {
        float b_rob = br2o[c];
        f16x8 Brob0 = load_bh(wsf, FR_ROB + 0, lane);
        f16x8 Brob1 = load_bh(wsf, FR_ROB + 1, lane);
        f16x8 A0 = lds_af(BIG, BIG_STR, 0, lane);
        f16x8 A1 = lds_af(BIG, BIG_STR, 64, lane);
        f32x4 ca = mfma1(A0, Brob0, cinit(b_rob));
        f32x4 cb = mfma1(A1, Brob1, ZC);
        #pragma unroll
        for (int reg = 0; reg < 4; ++reg)
            *(_Float16*)(CAT + (q * 4 + reg) * CAT_STR + (16 + c) * 2) = (_Float16)(ca[reg] + cb[reg]);
    }
    lds_order();

    // =================== PSI head ==========================================
    // PSI1 -> BIG (h3); bias via k=36 pad row in CAT hi-zone
    {
        f16x8 Bp1a[4], Bp1b[4];
        #pragma unroll
        for (int nt = 0; nt < 4; ++nt) Bp1a[nt] = load_bh(wsf, FR_PSI1 + nt, lane);
        #pragma unroll
        for (int nt = 0; nt < 4; ++nt) Bp1b[nt] = load_bh(wsf, FR_PSI1 + 4 + nt, lane);
        f16x8 A0 = lds_af(CAT, CAT_STR, 0, lane);    // k 0..31
        f16x8 A1 = lds_af(CAT, CAT_STR, 64, lane);   // k 32..63
        #pragma unroll
        for (int nt = 0; nt < 4; ++nt) {
            f32x4 ca = mfma1(A0, Bp1a[nt], ZC);
            f32x4 cb = mfma1(A1, Bp1b[nt], ZC);
            #pragma unroll
            for (int reg = 0; reg < 4; ++reg)
                *(_Float16*)(BIG + (q * 4 + reg) * BIG_STR + (nt * 16 + c) * 2) = (_Float16)fmaxf(ca[reg] + cb[reg], 0.f);
        }
    }
    lds_order();

    // PSI2 -> OUT
    {
        float b_p2 = (c < 2) ? bpsi2[c] : 0.f;
        f16x8 Bp20 = load_bh(wsf, FR_PSI2 + 0, lane);
        f16x8 Bp21 = load_bh(wsf, FR_PSI2 + 1, lane);
        f16x8 A0 = lds_af(BIG, BIG_STR, 0, lane);
        f16x8 A1 = lds_af(BIG, BIG_STR, 64, lane);
        f32x4 ca = mfma1(A0, Bp20, cinit(b_p2));
        f32x4 cb = mfma1(A1, Bp21, ZC);
        if (c < 2) {
            #pragma unroll
            for (int reg = 0; reg < 4; ++reg)
                *(float*)(OUTA + (q * 4 + reg) * 8 + c * 4) = ca[reg] + cb[reg];
        }
    }
    lds_order();

    // epilogue
    if (lane < 16) {
        float2 a  = *(const float2*)(OUTA + lane * 8);
        float2 bb = *(const float2*)(BAR + lane * 8);
        float a0 = two_tanh(a.x) + bb.x;
        float a1 = two_tanh(a.y) + bb.y;
        float amax = fmaxf(fabsf(a0), fabsf(a1));
        float inv_alpha = fmaxf(amax * 0.5f, 1.0f);
        float rr = fast_rcp(inv_alpha);
        float2 o; o.x = a0 * rr; o.y = a1 * rr;
        *(float2*)(out + (size_t)(row0 + lane) * 2) = o;
    }
}

extern "C" void kernel_launch(void* const* d_in, const int* in_sizes, int n_in,
                              void* d_out, int out_size, void* d_ws, size_t ws_size,
                              hipStream_t stream) {
    const float* x     = (const float*)d_in[0];
    const float* Wp1n  = (const float*)d_in[1];
    const float* bp1n  = (const float*)d_in[2];
    const float* Wp2n  = (const float*)d_in[3];
    const float* bp2n  = (const float*)d_in[4];
    const float* Wr1n  = (const float*)d_in[5];
    const float* br1n  = (const float*)d_in[6];
    const float* Wr2n  = (const float*)d_in[7];
    const float* br2n  = (const float*)d_in[8];
    const float* Wp1o  = (const float*)d_in[9];
    const float* bp1o  = (const float*)d_in[10];
    const float* Wp2o  = (const float*)d_in[11];
    const float* bp2o  = (const float*)d_in[12];
    const float* Wr1o  = (const float*)d_in[13];
    const float* br1o  = (const float*)d_in[14];
    const float* Wr2o  = (const float*)d_in[15];
    const float* br2o  = (const float*)d_in[16];
    const float* Wpsi1 = (const float*)d_in[17];
    const float* bpsi1 = (const float*)d_in[18];
    const float* Wpsi2 = (const float*)d_in[19];
    const float* bpsi2 = (const float*)d_in[20];
    float* out = (float*)d_out;

    int nb = in_sizes[0] / XW;               // 131072
    _Float16* wsf = (_Float16*)d_ws;         // ~34 KB frag table

    bn_prep<<<N_FRAGS, 64, 0, stream>>>(Wp1n, Wp2n, Wr1n, Wr2n,
                                        Wp1o, Wp2o, Wr1o, Wr2o,
                                        Wpsi1, Wpsi2,
                                        bp1n, bp1o, br1n, br1o, bpsi1,
                                        wsf);

    int groups = (nb + 15) / 16;             // 8192
    int blocks = (groups + 3) / 4;           // 2048 (4 groups per block)
    bn_main<<<blocks, 256, 0, stream>>>(x, wsf,
                                        bp2n, br2n, bp2o, br2o, bpsi2,
                                        out, nb);
}

// Round 4
// 137.359 us; speedup vs baseline: 1.0973x; 1.0578x over previous
//
#include <hip/hip_runtime.h>
#include <math.h>

// ---------------------------------------------------------------------------
// Barrier_Net, full-f16 MFMA (16x16x32), SINGLE-WAVE-PER-GROUP pipeline.
// One wave handles 16 batch rows END-TO-END (R15 structure, no __syncthreads).
// R16 changes vs R15 (145.3 us, bn_main ~42 us):
//   * S1N/S1O relu-sum via exact identity  Sum max(x,0) = (Sum x + Sum|x|)/2:
//       - Sum x  : C-chained MFMAs (zero VALU cost, idle matrix pipe)
//       - Sum|x| : second MFMA chain w/ C=0, accA += fabsf(cc) -> ONE v_add
//         (abs is a free VOP3 input modifier) instead of max+add per element.
//     Cuts the dominant VALU block 768 -> ~448 instrs/wave, +96 MFMA on the
//     13%-utilized matrix pipe.
//   * The 1/2 is folded into bn_prep: FR_G2N / FR_G2O weight frags scaled by
//     0.5 (h1 stored as 2*h1; G2N/G2O are its only consumers). Biases
//     unaffected (b_g2n/b_g2o enter via cinit, not through W).
//   * __launch_bounds__(256,5): VGPR cap 102 for the extra accS/accA live
//     range (R14/R15 proved occupancy-insensitivity above ~20 waves/CU).
// A-frag: A[m=lane&15][k=(lane>>4)*8+j]; B-frag: B[k=(lane>>4)*8+j][n=lane&15]
// C/D: col=lane&15, row=(lane>>4)*4+reg.  (HW-verified R7..R12)
// Biases embedded in spare K-rows of B-frags (R14): S1N k=4, S1O k=2,
// RNA/ROA k=16 (PHI pad 1.0), PSI1 k=36 (CAT pad 1.0).
// nb = 131072 = 64*2048 -> 2048 full blocks, no partial groups.
// ---------------------------------------------------------------------------

typedef __attribute__((ext_vector_type(8))) _Float16 f16x8;
typedef __attribute__((ext_vector_type(2))) __fp16 fp16x2;
typedef __attribute__((ext_vector_type(4))) float f32x4;

#define XW 85     // floats per input row

// ---- B-frag table in d_ws: 34 frags x 64 lanes x 8 f16 ----
#define FR_S1N  0
#define FR_S1O  4
#define FR_G2N  8
#define FR_G2O  10
#define FR_RNA  12
#define FR_RNB  16
#define FR_ROA  18
#define FR_ROB  22
#define FR_PSI1 24
#define FR_PSI2 32
#define N_FRAGS 34

// ---- per-GROUP LDS layout (bytes); 4 groups (waves) per 256-thread block ----
#define BIG_STR 144
#define PHI_STR 80
#define CAT_STR 144
#define L_BIG  0        // 2304  NBA staging / h1n / h1o / h3
#define L_PHI  2304     // 1280  phn / pho (k=16 bias pad written once)
#define L_CAT  3584     // 2304  concat tile (wave-private)
#define L_OUT  5888     // 128
#define L_BAR  6016     // 128
#define L_OBA  6144     // 544 = 8 obst tiles x 68 B
#define GRP_LDS 6688    // x4 groups = 26752 B/block
#define NBA_STR 136     // staging tile stride inside BIG region
#define OBA_STR 68

#define H16_ONE 0x00003C00u   // f16 1.0 in low half of a dword

__device__ __forceinline__ float fast_rcp(float x)  { return __builtin_amdgcn_rcpf(x); }
__device__ __forceinline__ float fast_sqrt(float x) { return __builtin_amdgcn_sqrtf(x); }

__device__ __forceinline__ float two_tanh(float a) {
    float ax = fabsf(a);
    float e = __expf(2.0f * ax);
    float t = 1.0f - 2.0f * fast_rcp(e + 1.0f);
    return copysignf(2.0f * t, a);
}

// Compiler-only ordering barrier for wave-private LDS (R11-proven safe).
__device__ __forceinline__ void lds_order() {
    __asm__ __volatile__("" ::: "memory");
}

__device__ __forceinline__ unsigned pk2(float a, float b) {
    union { fp16x2 h; unsigned u; } t;
    t.h = __builtin_amdgcn_cvt_pkrtz(a, b);
    return t.u;
}
__device__ __forceinline__ f16x8 lds_af(const char* area, int stride, int off, int lane) {
    int mm = lane & 15, qq = lane >> 4;
    return *(const f16x8*)(area + mm * stride + off + qq * 16);
}
__device__ __forceinline__ f16x8 load_bh(const _Float16* wsf, int frag, int lane) {
    return ((const f16x8*)(wsf + (size_t)frag * 512))[lane];
}
__device__ __forceinline__ f32x4 cinit(float b) {
    f32x4 c; c[0] = b; c[1] = b; c[2] = b; c[3] = b; return c;
}
__device__ __forceinline__ f32x4 mfma1(f16x8 a, f16x8 b, f32x4 c) {
    return __builtin_amdgcn_mfma_f32_16x16x32_f16(a, b, c, 0, 0, 0);
}

// ---------------------------------------------------------------------------
// prep: pack weights into f16 B-frag blocks, zero outside (K,N).
// Bias vector embedded at row K (first spare k-slot) where applicable (R14).
// R16: FR_G2N / FR_G2O weights pre-scaled by 0.5 (relu-identity fold).
// ---------------------------------------------------------------------------
__global__ void bn_prep(const float* __restrict__ Wp1n, const float* __restrict__ Wp2n,
                        const float* __restrict__ Wr1n, const float* __restrict__ Wr2n,
                        const float* __restrict__ Wp1o, const float* __restrict__ Wp2o,
                        const float* __restrict__ Wr1o, const float* __restrict__ Wr2o,
                        const float* __restrict__ Wpsi1, const float* __restrict__ Wpsi2,
                        const float* __restrict__ bp1n, const float* __restrict__ bp1o,
                        const float* __restrict__ br1n, const float* __restrict__ br1o,
                        const float* __restrict__ bpsi1,
                        _Float16* __restrict__ wsf)
{
    int f = blockIdx.x;
    int lane = threadIdx.x;   // 64
    const float* W; const float* bias = nullptr;
    int K, N, kk = 0, nt = 0, rel, kbias = -1;
    float wscale = 1.0f;
    if (f < 4)        { W = Wp1n;  K = 4;  N = 64; nt = f;      bias = bp1n;  kbias = 4; }
    else if (f < 8)   { W = Wp1o;  K = 2;  N = 64; nt = f - 4;  bias = bp1o;  kbias = 2; }
    else if (f < 10)  { W = Wp2n;  K = 64; N = 16; kk = f - 8;  wscale = 0.5f; }
    else if (f < 12)  { W = Wp2o;  K = 64; N = 16; kk = f - 10; wscale = 0.5f; }
    else if (f < 16)  { W = Wr1n;  K = 16; N = 64; nt = f - 12; bias = br1n;  kbias = 16; }
    else if (f < 18)  { W = Wr2n;  K = 64; N = 16; kk = f - 16; }
    else if (f < 22)  { W = Wr1o;  K = 16; N = 64; nt = f - 18; bias = br1o;  kbias = 16; }
    else if (f < 24)  { W = Wr2o;  K = 64; N = 16; kk = f - 22; }
    else if (f < 32)  { rel = f - 24; W = Wpsi1; K = 36; N = 64; kk = rel >> 2; nt = rel & 3;
                        bias = bpsi1; kbias = 36; }
    else              { W = Wpsi2; K = 64; N = 2;  kk = f - 32; }

    int q = lane >> 4, c = lane & 15;
    _Float16* dst = wsf + (size_t)f * 512 + lane * 8;
    for (int j = 0; j < 8; ++j) {
        int k = kk * 32 + q * 8 + j;
        int n = nt * 16 + c;
        float v = 0.f;
        if (n < N) {
            if (k < K) v = W[k * N + n] * wscale;
            else if (k == kbias) v = bias[n];
        }
        dst[j] = (_Float16)v;
    }
}

// ---------------------------------------------------------------------------
// main: 1 wave per 16-row group; block 256 = 4 independent waves/groups.
// ---------------------------------------------------------------------------
__global__ __launch_bounds__(256, 5) void bn_main(
    const float* __restrict__ x, const _Float16* __restrict__ wsf,
    const float* __restrict__ bp2n, const float* __restrict__ br2n,
    const float* __restrict__ bp2o, const float* __restrict__ br2o,
    const float* __restrict__ bpsi2,
    float* __restrict__ out, int nb)
{
    __shared__ char smem[4 * GRP_LDS];
    const int lane = threadIdx.x & 63;
    const int wid  = threadIdx.x >> 6;            // 0..3 = group within block
    const int group = blockIdx.x * 4 + wid;
    const int row0 = group * 16;                  // nb is exact multiple of 64

    char* Gl   = smem + wid * GRP_LDS;
    char* BIG  = Gl + L_BIG;
    char* PHI  = Gl + L_PHI;
    char* CAT  = Gl + L_CAT;
    char* OUTA = Gl + L_OUT;
    char* BAR  = Gl + L_BAR;
    char* OBA  = Gl + L_OBA;
    char* NBA  = BIG;                  // staging aliases BIG

    const int m = lane & 15, q = lane >> 4, c = m;
    const float* xg   = x + (size_t)row0 * XW;    // group base
    const float* xrow = xg + (size_t)m * XW;      // this lane's batch row

    const f32x4 ZC = cinit(0.f);       // shared zero C-operand (invariant)

    // ---- stage neighbor features -> NBA (= BIG) as packed f16 A-tiles ----
    {
        int ln5 = lane >> 5;                 // 0/1
        int pr  = lane & 31;
        int mm0 = pr >> 1, fp = pr & 1;
        char* db = NBA + mm0 * NBA_STR + fp * 4;
        const float* s0 = xg + (size_t)ln5 * XW + 5 + pr * 2;
        #pragma unroll
        for (int t = 0; t < 8; ++t) {
            const float* s = s0 + (size_t)(2 * t) * XW;
            *(unsigned*)(db + (2 * t + ln5) * 8) = pk2(s[0], s[1]);
        }
    }
    // ---- stage obstacle features -> OBA (separate region) ----
    {
        int r8 = lane >> 3;                  // 0..7
        int oo = lane & 7;
        char* db = OBA + oo * OBA_STR;
        const float* s0 = xg + (size_t)r8 * XW + 69 + oo * 2;
        #pragma unroll
        for (int t = 0; t < 2; ++t) {
            const float* s = s0 + (size_t)(8 * t) * XW;
            *(unsigned*)(db + (8 * t + r8) * 4) = pk2(s[0], s[1]);
        }
    }

    // ---- PHI pad (serves RNA *and* ROA): k=16 slot = f16 1.0, rest zero ----
    {
        unsigned zv = ((lane & 7) == 0) ? H16_ONE : 0u;
        for (int i = lane; i < 128; i += 64) {
            int r = i >> 3, d = i & 7;
            *(unsigned*)(PHI + r * PHI_STR + 32 + d * 4) = zv;
        }
    }
    // ---- CAT hi-zone (k=32..63): k=36 slot = f16 1.0 (PSI1 bias), rest 0 ----
    {
        unsigned zc = ((lane & 15) == 2) ? H16_ONE : 0u;
        for (int i = lane; i < 256; i += 64) {
            int r = i >> 4, d = i & 15;
            *(unsigned*)(CAT + r * CAT_STR + 64 + d * 4) = zc;
        }
    }
    // ---- g -> CAT k=32..35 (same wave, DS in-order after zeros) ----
    if (lane < 16) {
        const float* xr = x + (size_t)(row0 + lane) * XW;
        uint2 gv;
        gv.x = pk2(xr[1], xr[2]);
        gv.y = pk2(xr[3], xr[4]);
        *(uint2*)(CAT + lane * CAT_STR + 64) = gv;
    }

    // ---- barrier terms: lane (row m, quad q): nbrs 4q..4q+3, obs 2q..2q+1 ----
    // (kept on raw f32 global reads: f16-staged inputs would lose precision
    //  near the nrm ~ D pole)
    {
        float bx = 0.f, by = 0.f;
        #pragma unroll
        for (int i = 0; i < 4; ++i) {
            int n = 4 * q + i;
            float px = -xrow[5 + 4 * n], py = -xrow[6 + 4 * n];
            float nrm = fast_sqrt(px * px + py * py);
            float coef = 0.05f * fast_rcp(nrm * (nrm - 0.3f));
            bx = fmaf(coef, px, bx);
            by = fmaf(coef, py, by);
        }
        #pragma unroll
        for (int i = 0; i < 2; ++i) {
            int o = 2 * q + i;
            float px = -xrow[69 + 2 * o], py = -xrow[70 + 2 * o];
            float nrm = fast_sqrt(px * px + py * py);
            float coef = 0.05f * fast_rcp(nrm * (nrm - 0.3f));
            bx = fmaf(coef, px, bx);
            by = fmaf(coef, py, by);
        }
        bx += __shfl_xor(bx, 16); by += __shfl_xor(by, 16);
        bx += __shfl_xor(bx, 32); by += __shfl_xor(by, 32);
        if (q == 0) { float2 bb; bb.x = bx; bb.y = by; *(float2*)(BAR + m * 8) = bb; }
    }
    lds_order();

    // =================== neighbor chain ====================================
    // S1N: Sum_m relu(x_m) = (Sum_m x_m + Sum_m |x_m|) / 2.
    //   accS: MFMA C-chained (no VALU).  accA: += fabsf(cc) (1 VALU/elem).
    //   The /2 is folded into the pre-halved FR_G2N weights; store S+A = 2*h1.
    {
        f16x8 Bs1n[4];
        #pragma unroll
        for (int nt = 0; nt < 4; ++nt) Bs1n[nt] = load_bh(wsf, FR_S1N + nt, lane);

        const int m8 = m * 8;
        f32x4 accS[4], accA[4];
        #pragma unroll
        for (int nt = 0; nt < 4; ++nt) { accS[nt] = cinit(0.f); accA[nt] = cinit(0.f); }
        union { f16x8 v; unsigned u[4]; uint2 h[2]; } A;
        A.u[2] = H16_ONE; A.u[3] = 0;        // k=4 bias slot
        #pragma unroll
        for (int mm = 0; mm < 16; ++mm) {
            A.h[0] = *(const uint2*)(NBA + mm * NBA_STR + m8);
            #pragma unroll
            for (int nt = 0; nt < 4; ++nt) {
                accS[nt] = mfma1(A.v, Bs1n[nt], accS[nt]);   // Sum x (free)
                f32x4 cc = mfma1(A.v, Bs1n[nt], ZC);         // per-term x
                #pragma unroll
                for (int reg = 0; reg < 4; ++reg)
                    accA[nt][reg] += fabsf(cc[reg]);         // Sum |x|, 1 VALU
            }
        }
        lds_order();   // NBA reads done; BIG stores below alias it
        #pragma unroll
        for (int nt = 0; nt < 4; ++nt)
            #pragma unroll
            for (int reg = 0; reg < 4; ++reg)
                *(_Float16*)(BIG + (q * 4 + reg) * BIG_STR + (nt * 16 + c) * 2)
                    = (_Float16)(accS[nt][reg] + accA[nt][reg]);
    }
    lds_order();

    // G2N -> PHI (phn)   [weights pre-halved in prep]
    {
        float b_g2n = 16.f * bp2n[c];
        f16x8 Bg2n0 = load_bh(wsf, FR_G2N + 0, lane);
        f16x8 Bg2n1 = load_bh(wsf, FR_G2N + 1, lane);
        f16x8 A0 = lds_af(BIG, BIG_STR, 0, lane);
        f16x8 A1 = lds_af(BIG, BIG_STR, 64, lane);
        f32x4 ca = mfma1(A0, Bg2n0, cinit(b_g2n));
        f32x4 cb = mfma1(A1, Bg2n1, ZC);
        #pragma unroll
        for (int reg = 0; reg < 4; ++reg)
            *(_Float16*)(PHI + (q * 4 + reg) * PHI_STR + c * 2) = (_Float16)(ca[reg] + cb[reg]);
    }
    lds_order();

    // RNA -> BIG (bias via k=16 pad row)
    {
        f16x8 Brna[4];
        #pragma unroll
        for (int nt = 0; nt < 4; ++nt) Brna[nt] = load_bh(wsf, FR_RNA + nt, lane);
        f16x8 A = lds_af(PHI, PHI_STR, 0, lane);
        #pragma unroll
        for (int nt = 0; nt < 4; ++nt) {
            f32x4 cc = mfma1(A, Brna[nt], ZC);
            #pragma unroll
            for (int reg = 0; reg < 4; ++reg)
                *(_Float16*)(BIG + (q * 4 + reg) * BIG_STR + (nt * 16 + c) * 2) = (_Float16)fmaxf(cc[reg], 0.f);
        }
    }
    lds_order();

    // RNB -> CAT cols 0..15
    {
        float b_rnb = br2n[c];
        f16x8 Brnb0 = load_bh(wsf, FR_RNB + 0, lane);
        f16x8 Brnb1 = load_bh(wsf, FR_RNB + 1, lane);
        f16x8 A0 = lds_af(BIG, BIG_STR, 0, lane);
        f16x8 A1 = lds_af(BIG, BIG_STR, 64, lane);
        f32x4 ca = mfma1(A0, Brnb0, cinit(b_rnb));
        f32x4 cb = mfma1(A1, Brnb1, ZC);
        #pragma unroll
        for (int reg = 0; reg < 4; ++reg)
            *(_Float16*)(CAT + (q * 4 + reg) * CAT_STR + c * 2) = (_Float16)(ca[reg] + cb[reg]);
    }
    lds_order();

    // =================== obstacle chain ====================================
    // S1O: same relu-identity restructure (8 terms; FR_G2O pre-halved).
    {
        f16x8 Bs1o[4];
        #pragma unroll
        for (int nt = 0; nt < 4; ++nt) Bs1o[nt] = load_bh(wsf, FR_S1O + nt, lane);

        const int m4 = m * 4;
        f32x4 accS[4], accA[4];
        #pragma unroll
        for (int nt = 0; nt < 4; ++nt) { accS[nt] = cinit(0.f); accA[nt] = cinit(0.f); }
        union { f16x8 v; unsigned u[4]; } A;
        A.u[1] = H16_ONE; A.u[2] = 0; A.u[3] = 0;   // k=2 bias slot
        #pragma unroll
        for (int oo = 0; oo < 8; ++oo) {
            A.u[0] = *(const unsigned*)(OBA + oo * OBA_STR + m4);
            #pragma unroll
            for (int nt = 0; nt < 4; ++nt) {
                accS[nt] = mfma1(A.v, Bs1o[nt], accS[nt]);
                f32x4 cc = mfma1(A.v, Bs1o[nt], ZC);
                #pragma unroll
                for (int reg = 0; reg < 4; ++reg)
                    accA[nt][reg] += fabsf(cc[reg]);
            }
        }
        lds_order();   // BIG (h1n) reads done (RNB above); safe to overwrite
        #pragma unroll
        for (int nt = 0; nt < 4; ++nt)
            #pragma unroll
            for (int reg = 0; reg < 4; ++reg)
                *(_Float16*)(BIG + (q * 4 + reg) * BIG_STR + (nt * 16 + c) * 2)
                    = (_Float16)(accS[nt][reg] + accA[nt][reg]);
    }
    lds_order();

    // G2O -> PHI (pho; pad row still intact)   [weights pre-halved in prep]
    {
        float b_g2o = 8.f * bp2o[c];
        f16x8 Bg2o0 = load_bh(wsf, FR_G2O + 0, lane);
        f16x8 Bg2o1 = load_bh(wsf, FR_G2O + 1, lane);
        f16x8 A0 = lds_af(BIG, BIG_STR, 0, lane);
        f16x8 A1 = lds_af(BIG, BIG_STR, 64, lane);
        f32x4 ca = mfma1(A0, Bg2o0, cinit(b_g2o));
        f32x4 cb = mfma1(A1, Bg2o1, ZC);
        #pragma unroll
        for (int reg = 0; reg < 4; ++reg)
            *(_Float16*)(PHI + (q * 4 + reg) * PHI_STR + c * 2) = (_Float16)(ca[reg] + cb[reg]);
    }
    lds_order();

    // ROA -> BIG (bias via k=16 pad row)
    {
        f16x8 Broa[4];
        #pragma unroll
        for (int nt = 0; nt < 4; ++nt) Broa[nt] = load_bh(wsf, FR_ROA + nt, lane);
        f16x8 A = lds_af(PHI, PHI_STR, 0, lane);
        #pragma unroll
        for (int nt = 0; nt < 4; ++nt) {
            f32x4 cc = mfma1(A, Broa[nt], ZC);
            #pragma unroll
            for (int reg = 0; reg < 4; ++reg)
                *(_Float16*)(BIG + (q * 4 + reg) * BIG_STR + (nt * 16 + c) * 2) = (_Float16)fmaxf(cc[reg], 0.f);
        }
    }
    lds_order();

    // ROB -> CAT cols 16..31
    {
        float b_rob = br2o[c];
        f16x8 Brob0 = load_bh(wsf, FR_ROB + 0, lane);
        f16x8 Brob1 = load_bh(wsf, FR_ROB + 1, lane);
        f16x8 A0 = lds_af(BIG, BIG_STR, 0, lane);
        f16x8 A1 = lds_af(BIG, BIG_STR, 64, lane);
        f32x4 ca = mfma1(A0, Brob0, cinit(b_rob));
        f32x4 cb = mfma1(A1, Brob1, ZC);
        #pragma unroll
        for (int reg = 0; reg < 4; ++reg)
            *(_Float16*)(CAT + (q * 4 + reg) * CAT_STR + (16 + c) * 2) = (_Float16)(ca[reg] + cb[reg]);
    }
    lds_order();

    // =================== PSI head ==========================================
    // PSI1 -> BIG (h3); bias via k=36 pad row in CAT hi-zone
    {
        f16x8 Bp1a[4], Bp1b[4];
        #pragma unroll
        for (int nt = 0; nt < 4; ++nt) Bp1a[nt] = load_bh(wsf, FR_PSI1 + nt, lane);
        #pragma unroll
        for (int nt = 0; nt < 4; ++nt) Bp1b[nt] = load_bh(wsf, FR_PSI1 + 4 + nt, lane);
        f16x8 A0 = lds_af(CAT, CAT_STR, 0, lane);    // k 0..31
        f16x8 A1 = lds_af(CAT, CAT_STR, 64, lane);   // k 32..63
        #pragma unroll
        for (int nt = 0; nt < 4; ++nt) {
            f32x4 ca = mfma1(A0, Bp1a[nt], ZC);
            f32x4 cb = mfma1(A1, Bp1b[nt], ZC);
            #pragma unroll
            for (int reg = 0; reg < 4; ++reg)
                *(_Float16*)(BIG + (q * 4 + reg) * BIG_STR + (nt * 16 + c) * 2) = (_Float16)fmaxf(ca[reg] + cb[reg], 0.f);
        }
    }
    lds_order();

    // PSI2 -> OUT
    {
        float b_p2 = (c < 2) ? bpsi2[c] : 0.f;
        f16x8 Bp20 = load_bh(wsf, FR_PSI2 + 0, lane);
        f16x8 Bp21 = load_bh(wsf, FR_PSI2 + 1, lane);
        f16x8 A0 = lds_af(BIG, BIG_STR, 0, lane);
        f16x8 A1 = lds_af(BIG, BIG_STR, 64, lane);
        f32x4 ca = mfma1(A0, Bp20, cinit(b_p2));
        f32x4 cb = mfma1(A1, Bp21, ZC);
        if (c < 2) {
            #pragma unroll
            for (int reg = 0; reg < 4; ++reg)
                *(float*)(OUTA + (q * 4 + reg) * 8 + c * 4) = ca[reg] + cb[reg];
        }
    }
    lds_order();

    // epilogue
    if (lane < 16) {
        float2 a  = *(const float2*)(OUTA + lane * 8);
        float2 bb = *(const float2*)(BAR + lane * 8);
        float a0 = two_tanh(a.x) + bb.x;
        float a1 = two_tanh(a.y) + bb.y;
        float amax = fmaxf(fabsf(a0), fabsf(a1));
        float inv_alpha = fmaxf(amax * 0.5f, 1.0f);
        float rr = fast_rcp(inv_alpha);
        float2 o; o.x = a0 * rr; o.y = a1 * rr;
        *(float2*)(out + (size_t)(row0 + lane) * 2) = o;
    }
}

extern "C" void kernel_launch(void* const* d_in, const int* in_sizes, int n_in,
                              void* d_out, int out_size, void* d_ws, size_t ws_size,
                              hipStream_t stream) {
    const float* x     = (const float*)d_in[0];
    const float* Wp1n  = (const float*)d_in[1];
    const float* bp1n  = (const float*)d_in[2];
    const float* Wp2n  = (const float*)d_in[3];
    const float* bp2n  = (const float*)d_in[4];
    const float* Wr1n  = (const float*)d_in[5];
    const float* br1n  = (const float*)d_in[6];
    const float* Wr2n  = (const float*)d_in[7];
    const float* br2n  = (const float*)d_in[8];
    const float* Wp1o  = (const float*)d_in[9];
    const float* bp1o  = (const float*)d_in[10];
    const float* Wp2o  = (const float*)d_in[11];
    const float* bp2o  = (const float*)d_in[12];
    const float* Wr1o  = (const float*)d_in[13];
    const float* br1o  = (const float*)d_in[14];
    const float* Wr2o  = (const float*)d_in[15];
    const float* br2o  = (const float*)d_in[16];
    const float* Wpsi1 = (const float*)d_in[17];
    const float* bpsi1 = (const float*)d_in[18];
    const float* Wpsi2 = (const float*)d_in[19];
    const float* bpsi2 = (const float*)d_in[20];
    float* out = (float*)d_out;

    int nb = in_sizes[0] / XW;               // 131072
    _Float16* wsf = (_Float16*)d_ws;         // ~34 KB frag table

    bn_prep<<<N_FRAGS, 64, 0, stream>>>(Wp1n, Wp2n, Wr1n, Wr2n,
                                        Wp1o, Wp2o, Wr1o, Wr2o,
                                        Wpsi1, Wpsi2,
                                        bp1n, bp1o, br1n, br1o, bpsi1,
                                        wsf);

    int groups = (nb + 15) / 16;             // 8192
    int blocks = (groups + 3) / 4;           // 2048 (4 groups per block)
    bn_main<<<blocks, 256, 0, stream>>>(x, wsf,
                                        bp2n, br2n, bp2o, br2o, bpsi2,
                                        out, nb);
}